// Round 12
// baseline (4620.354 us; speedup 1.0000x reference)
//
#include <hip/hip_runtime.h>
#include <math.h>

typedef unsigned short u16;
typedef unsigned int u32;

#define FEATN 66
#define HIDN 256
#define NNDIM 16896      // 66*256
#define INVS 0.9999950000374998f
#ifndef M_PI
#define M_PI 3.14159265358979323846
#endif

typedef __attribute__((ext_vector_type(4))) float f32x4;
typedef __attribute__((ext_vector_type(2))) float f32x2;
typedef __attribute__((ext_vector_type(8))) short s16x8;

__device__ __forceinline__ u32 bf_rne(float x) {
    u32 i = __float_as_uint(x);
    return (i + 0x7fffu + ((i >> 16) & 1u)) >> 16;
}

// ---------------- DCT matrix (parallel build; orthonormal: inv = transpose) ----------------
__global__ void dct_kernel(float* __restrict__ dct) {
    int t = threadIdx.x;
    if (t < 400) {
        int k = t / 20, i = t % 20;
        double w = (k == 0) ? sqrt(1.0 / 20.0) : sqrt(2.0 / 20.0);
        dct[t] = (float)(w * cos(M_PI * (i + 0.5) * k / 20.0));
    }
}

// ---------------- pack blk_w into split-bf16 MFMA B-fragment layout ----------------
// index within layer: (ks*16 + ct)*512 + lane*8 + j ; value = W[k=ks*32+(lane>>4)*8+j][n=ct*16+(lane&15)]
__global__ __launch_bounds__(256) void pack_w_kernel(
    const float* __restrict__ blk_w, u16* __restrict__ wh, u16* __restrict__ wl) {
    int gid = blockIdx.x * 256 + threadIdx.x;
    if (gid >= 12 * 65536) return;
    int layer = gid >> 16, rmd = gid & 65535;
    int ks = rmd >> 13;
    int r2 = rmd & 8191;
    int ct = r2 >> 9;
    int r3 = r2 & 511;
    int lane = r3 >> 3, j = r3 & 7;
    int k = ks * 32 + (lane >> 4) * 8 + j;
    int n = ct * 16 + (lane & 15);
    float v = blk_w[(size_t)layer * 65536 + k * 256 + n];
    u32 rhi = bf_rne(v);
    float hif = __uint_as_float(rhi << 16);
    u32 rlo = bf_rne(v - hif);
    wh[gid] = (u16)rhi;
    wl[gid] = (u16)rlo;
}

// ---------------- pack conv2 weights, K reordered t-major: k' = t*256 + h ----------------
__global__ __launch_bounds__(256) void pack_w2_kernel(
    const float* __restrict__ w2, u16* __restrict__ wh, u16* __restrict__ wl) {
    int gid = blockIdx.x * 256 + threadIdx.x;
    if (gid >= 40 * 16 * 512) return;
    int ks = gid >> 13;
    int r2 = gid & 8191;
    int ct = r2 >> 9;
    int r3 = r2 & 511;
    int lane = r3 >> 3, j = r3 & 7;
    int k = ks * 32 + (lane >> 4) * 8 + j;
    int n = ct * 16 + (lane & 15);
    int h = k & 255, t = k >> 8;
    float v = w2[(size_t)n * 1280 + h * 5 + t];
    u32 rhi = bf_rne(v);
    float hif = __uint_as_float(rhi << 16);
    u32 rlo = bf_rne(v - hif);
    wh[gid] = (u16)rhi;
    wl[gid] = (u16)rlo;
}

// ---------------- pack conv1 weights, K reordered t-major: k' = t*66 + f (pad to 416) ----------------
__global__ __launch_bounds__(256) void pack_w1_kernel(
    const float* __restrict__ w1, u16* __restrict__ wh, u16* __restrict__ wl) {
    int gid = blockIdx.x * 256 + threadIdx.x;
    if (gid >= 13 * 16 * 512) return;
    int ks = gid >> 13;
    int r2 = gid & 8191;
    int ct = r2 >> 9;
    int r3 = r2 & 511;
    int lane = r3 >> 3, j = r3 & 7;
    int k = ks * 32 + (lane >> 4) * 8 + j;
    int n = ct * 16 + (lane & 15);
    float v = 0.f;
    if (k < 396) {
        int f = k % 66, t = k / 66;
        v = w1[(size_t)n * 396 + f * 6 + t];
    }
    u32 rhi = bf_rne(v);
    float hif = __uint_as_float(rhi << 16);
    u32 rlo = bf_rne(v - hif);
    wh[gid] = (u16)rhi;
    wl[gid] = (u16)rlo;
}

// ---------------- pack blk_att into split-bf16 MFMA A-fragment layout ----------------
__global__ __launch_bounds__(256) void pack_att_kernel(
    const float* __restrict__ blk_att, u16* __restrict__ ah, u16* __restrict__ al) {
    int gid = blockIdx.x * 256 + threadIdx.x;
    if (gid >= 12 * 7680) return;
    int layer = gid / 7680, rem = gid % 7680;
    int rt = rem / 1536, rem2 = rem % 1536;
    int ks = rem2 / 512, r3 = rem2 % 512;
    int lane = r3 >> 3, j = r3 & 7;
    int n = rt * 16 + (lane & 15);
    int k = ks * 32 + (lane >> 4) * 8 + j;
    float v = (n < 66 && k < 66) ? blk_att[(size_t)layer * 4356 + n * 66 + k] : 0.f;
    u32 rhi = bf_rne(v);
    float hif = __uint_as_float(rhi << 16);
    u32 rlo = bf_rne(v - hif);
    ah[gid] = (u16)rhi;
    al[gid] = (u16)rlo;
}

// ---------------- conv1 as MFMA GEMM (split-bf16), q+k merged: N=256, K=396(pad 416) ----------------
__global__ __launch_bounds__(256, 1) void conv1_mfma_kernel(
    const float* __restrict__ x,
    const u16* __restrict__ whq, const u16* __restrict__ wlq,
    const u16* __restrict__ whk, const u16* __restrict__ wlk,
    const float* __restrict__ bq, const float* __restrict__ bk,
    float* __restrict__ q1, float* __restrict__ k1, int Cc, int nbq) {
    __shared__ u16 Ah[64 * 136];
    __shared__ u16 Al[64 * 136];
    const int tid = threadIdx.x;
    const int lane = tid & 63, wid = tid >> 6;
    const int m = lane & 15, quad = lane >> 4;
    const bool isq = ((int)blockIdx.x < nbq);
    const int bid = isq ? (int)blockIdx.x : ((int)blockIdx.x - nbq);
    const int rows = isq ? Cc * 5 : Cc * 35;
    const int row0 = bid * 64;
    const u16* wh = isq ? whq : whk;
    const u16* wl = isq ? wlq : wlk;
    const float* bias = isq ? bq : bk;
    float* out = isq ? q1 : k1;

    const int cq = tid & 31;
    const int r0t = (tid >> 5) * 8;
    int rbc[8]; bool vld[8];
#pragma unroll
    for (int s = 0; s < 8; s++) {
        int grow = row0 + r0t + s;
        int rbv;
        if (isq) { int bb = grow / 5;  rbv = bb * 3300 + 2640 + (grow - bb * 5) * 66; }
        else     { int bb = grow / 35; rbv = bb * 3300 + (grow - bb * 35) * 66; }
        vld[s] = (grow < rows);
        rbc[s] = vld[s] ? rbv : 0;
    }

    f32x4 acc[4][4];
#pragma unroll
    for (int rt = 0; rt < 4; rt++)
#pragma unroll
        for (int ct = 0; ct < 4; ct++) acc[rt][ct] = (f32x4)0.f;

    f32x2 ldA[16], ldB[16];

    auto LOADP = [&](f32x2* dst, int ph) {
        const int off = ph * 128 + cq * 4;
        const bool kok = (off < 396);
        const int o = kok ? off : 0;
#pragma unroll
        for (int s = 0; s < 8; s++) {
            const float* p = x + rbc[s] + o;
            dst[2 * s]     = *(const f32x2*)p;
            dst[2 * s + 1] = *(const f32x2*)(p + 2);
        }
    };
    auto STOREP = [&](const f32x2* src, int ph) {
        const bool kok = (ph * 128 + cq * 4) < 396;
#pragma unroll
        for (int s = 0; s < 8; s++) {
            float v0 = src[2 * s][0], v1 = src[2 * s][1];
            float v2 = src[2 * s + 1][0], v3 = src[2 * s + 1][1];
            if (!vld[s] || !kok) { v0 = v1 = v2 = v3 = 0.f; }
            u32 H0 = bf_rne(v0), H1 = bf_rne(v1), H2 = bf_rne(v2), H3 = bf_rne(v3);
            u32 L0 = bf_rne(v0 - __uint_as_float(H0 << 16));
            u32 L1 = bf_rne(v1 - __uint_as_float(H1 << 16));
            u32 L2 = bf_rne(v2 - __uint_as_float(H2 << 16));
            u32 L3 = bf_rne(v3 - __uint_as_float(H3 << 16));
            int o = (r0t + s) * 136 + cq * 4;
            *(uint2*)&Ah[o] = make_uint2(H0 | (H1 << 16), H2 | (H3 << 16));
            *(uint2*)&Al[o] = make_uint2(L0 | (L1 << 16), L2 | (L3 << 16));
        }
    };
    auto MFMAP = [&](int ph) {
#pragma unroll
        for (int ks = 0; ks < 4; ks++) {
            const int ksg = ph * 4 + ks;
            if (ksg >= 13) break;
            s16x8 ahf[4], alf[4], bhf[4], blf[4];
#pragma unroll
            for (int rt = 0; rt < 4; rt++) {
                int o2 = (rt * 16 + m) * 136 + ks * 32 + quad * 8;
                ahf[rt] = *(const s16x8*)&Ah[o2];
                alf[rt] = *(const s16x8*)&Al[o2];
            }
#pragma unroll
            for (int ct = 0; ct < 4; ct++) {
                size_t boff = ((size_t)(ksg * 16 + wid * 4 + ct)) * 512 + lane * 8;
                bhf[ct] = *(const s16x8*)&wh[boff];
                blf[ct] = *(const s16x8*)&wl[boff];
            }
#pragma unroll
            for (int rt = 0; rt < 4; rt++) {
#pragma unroll
                for (int ct = 0; ct < 4; ct++) {
                    acc[rt][ct] = __builtin_amdgcn_mfma_f32_16x16x32_bf16(
                        ahf[rt], bhf[ct], acc[rt][ct], 0, 0, 0);
                    acc[rt][ct] = __builtin_amdgcn_mfma_f32_16x16x32_bf16(
                        ahf[rt], blf[ct], acc[rt][ct], 0, 0, 0);
                    acc[rt][ct] = __builtin_amdgcn_mfma_f32_16x16x32_bf16(
                        alf[rt], bhf[ct], acc[rt][ct], 0, 0, 0);
                }
            }
        }
    };

    LOADP(ldA, 0);
    for (int ph = 0; ph < 4; ph += 2) {
        __syncthreads();
        STOREP(ldA, ph);
        LOADP(ldB, ph + 1);
        __syncthreads();
        MFMAP(ph);
        __syncthreads();
        STOREP(ldB, ph + 1);
        if (ph + 2 < 4) LOADP(ldA, ph + 2);
        __syncthreads();
        MFMAP(ph + 1);
    }

#pragma unroll
    for (int rt = 0; rt < 4; rt++) {
        int rb2 = row0 + rt * 16 + quad * 4;
#pragma unroll
        for (int r = 0; r < 4; r++) {
            int grow = rb2 + r;
            if (grow >= rows) continue;
#pragma unroll
            for (int ct = 0; ct < 4; ct++) {
                int f = wid * 64 + ct * 16 + m;
                float v = acc[rt][ct][r] + bias[f];
                out[(size_t)grow * 256 + f] = fmaxf(v, 0.f);
            }
        }
    }
}

// ---------------- conv2 as MFMA GEMM (split-bf16), q+k merged: N=256, K=1280 ----------------
__global__ __launch_bounds__(256, 1) void conv2_mfma_kernel(
    const float* __restrict__ Aq, const float* __restrict__ Ak,
    const u16* __restrict__ whq, const u16* __restrict__ wlq,
    const u16* __restrict__ whk, const u16* __restrict__ wlk,
    const float* __restrict__ bq, const float* __restrict__ bk,
    float* __restrict__ q2, float* __restrict__ k2, int Cc, int nbq) {
    __shared__ u16 Ah[64 * 136];
    __shared__ u16 Al[64 * 136];
    const int tid = threadIdx.x;
    const int lane = tid & 63, wid = tid >> 6;
    const int m = lane & 15, quad = lane >> 4;
    const bool isq = ((int)blockIdx.x < nbq);
    const int bid = isq ? (int)blockIdx.x : ((int)blockIdx.x - nbq);
    const int rows = isq ? Cc : Cc * 31;
    const int row0 = bid * 64;
    const float* Asrc = isq ? Aq : Ak;
    const u16* wh = isq ? whq : whk;
    const u16* wl = isq ? wlq : wlk;
    const float* bias = isq ? bq : bk;
    float* out = isq ? q2 : k2;

    const int cq = tid & 31;
    const int r0t = (tid >> 5) * 8;
    int rbc[8]; bool vld[8];
#pragma unroll
    for (int s = 0; s < 8; s++) {
        int grow = row0 + r0t + s;
        int rbv;
        if (isq) rbv = grow * 1280;
        else { int bb = grow / 31; rbv = bb * 8960 + (grow - bb * 31) * 256; }
        vld[s] = (grow < rows);
        rbc[s] = vld[s] ? rbv : 0;
    }

    f32x4 acc[4][4];
#pragma unroll
    for (int rt = 0; rt < 4; rt++)
#pragma unroll
        for (int ct = 0; ct < 4; ct++) acc[rt][ct] = (f32x4)0.f;

    f32x4 ldA[8], ldB[8];

    auto LOADP = [&](f32x4* dst, int ph) {
        const int off = ph * 128 + cq * 4;
#pragma unroll
        for (int s = 0; s < 8; s++)
            dst[s] = *(const f32x4*)(Asrc + rbc[s] + off);
    };
    auto STOREP = [&](const f32x4* src) {
#pragma unroll
        for (int s = 0; s < 8; s++) {
            f32x4 v = src[s];
            if (!vld[s]) v = (f32x4)0.f;
            u32 H0 = bf_rne(v[0]), H1 = bf_rne(v[1]), H2 = bf_rne(v[2]), H3 = bf_rne(v[3]);
            u32 L0 = bf_rne(v[0] - __uint_as_float(H0 << 16));
            u32 L1 = bf_rne(v[1] - __uint_as_float(H1 << 16));
            u32 L2 = bf_rne(v[2] - __uint_as_float(H2 << 16));
            u32 L3 = bf_rne(v[3] - __uint_as_float(H3 << 16));
            int o = (r0t + s) * 136 + cq * 4;
            *(uint2*)&Ah[o] = make_uint2(H0 | (H1 << 16), H2 | (H3 << 16));
            *(uint2*)&Al[o] = make_uint2(L0 | (L1 << 16), L2 | (L3 << 16));
        }
    };
    auto MFMAP = [&](int ph) {
#pragma unroll
        for (int ks = 0; ks < 4; ks++) {
            const int ksg = ph * 4 + ks;
            s16x8 ahf[4], alf[4], bhf[4], blf[4];
#pragma unroll
            for (int rt = 0; rt < 4; rt++) {
                int o2 = (rt * 16 + m) * 136 + ks * 32 + quad * 8;
                ahf[rt] = *(const s16x8*)&Ah[o2];
                alf[rt] = *(const s16x8*)&Al[o2];
            }
#pragma unroll
            for (int ct = 0; ct < 4; ct++) {
                size_t boff = ((size_t)(ksg * 16 + wid * 4 + ct)) * 512 + lane * 8;
                bhf[ct] = *(const s16x8*)&wh[boff];
                blf[ct] = *(const s16x8*)&wl[boff];
            }
#pragma unroll
            for (int rt = 0; rt < 4; rt++) {
#pragma unroll
                for (int ct = 0; ct < 4; ct++) {
                    acc[rt][ct] = __builtin_amdgcn_mfma_f32_16x16x32_bf16(
                        ahf[rt], bhf[ct], acc[rt][ct], 0, 0, 0);
                    acc[rt][ct] = __builtin_amdgcn_mfma_f32_16x16x32_bf16(
                        ahf[rt], blf[ct], acc[rt][ct], 0, 0, 0);
                    acc[rt][ct] = __builtin_amdgcn_mfma_f32_16x16x32_bf16(
                        alf[rt], bhf[ct], acc[rt][ct], 0, 0, 0);
                }
            }
        }
    };

    LOADP(ldA, 0);
    for (int ph = 0; ph < 10; ph += 2) {
        __syncthreads();
        STOREP(ldA);
        LOADP(ldB, ph + 1);
        __syncthreads();
        MFMAP(ph);
        __syncthreads();
        STOREP(ldB);
        if (ph + 2 < 10) LOADP(ldA, ph + 2);
        __syncthreads();
        MFMAP(ph + 1);
    }

#pragma unroll
    for (int rt = 0; rt < 4; rt++) {
        int rb2 = row0 + rt * 16 + quad * 4;
#pragma unroll
        for (int r = 0; r < 4; r++) {
            int grow = rb2 + r;
            if (grow >= rows) continue;
#pragma unroll
            for (int ct = 0; ct < 4; ct++) {
                int f = wid * 64 + ct * 16 + m;
                float v = acc[rt][ct][r] + bias[f];
                out[(size_t)grow * 256 + f] = fmaxf(v, 0.f);
            }
        }
    }
}

// ---------------- attention weights (one wave per batch); k2 layout [b][s][c] ----------------
__global__ void att_kernel(const float* __restrict__ q2, const float* __restrict__ k2,
                           float* __restrict__ att) {
    __shared__ float q2s[256];
    const int b = blockIdx.x, tid = threadIdx.x;
    for (int i = tid; i < 256; i += 64) q2s[i] = q2[(size_t)b * 256 + i];
    __syncthreads();
    float sc = 0.f;
    if (tid < 31) {
        const f32x4* kp = (const f32x4*)(k2 + (size_t)b * 7936 + tid * 256);
        for (int c = 0; c < 64; c++) {
            f32x4 kv = kp[c];
            sc = fmaf(q2s[c * 4 + 0], kv[0], sc);
            sc = fmaf(q2s[c * 4 + 1], kv[1], sc);
            sc = fmaf(q2s[c * 4 + 2], kv[2], sc);
            sc = fmaf(q2s[c * 4 + 3], kv[3], sc);
        }
    }
    float tot = sc;
#pragma unroll
    for (int off = 1; off < 64; off <<= 1) tot += __shfl_xor(tot, off);
    if (tid < 31) att[(size_t)b * 32 + tid] = (tot != 0.f) ? (sc / tot) : 0.f;
}

// ---------------- gcn_inp = concat(padded_query, att_final) ----------------
__global__ __launch_bounds__(256) void gcn_inp_kernel(
    const float* __restrict__ x, const float* __restrict__ att,
    const float* __restrict__ dct, float* __restrict__ ginp) {
    __shared__ float xs[3300];
    __shared__ float dctS[400];
    __shared__ float attS[31];
    const int b = blockIdx.x, tid = threadIdx.x;
    const float* xb = x + (size_t)b * 3300;
    for (int idx = tid; idx < 3300; idx += 256) xs[idx] = xb[idx];
    for (int idx = tid; idx < 400; idx += 256) dctS[idx] = dct[idx];
    if (tid < 31) attS[tid] = att[(size_t)b * 32 + tid];
    __syncthreads();
    for (int idx = tid; idx < 2640; idx += 256) {
        int n = idx / 40, l = idx - n * 40;
        float acc = 0.f;
        if (l < 20) {
#pragma unroll
            for (int l1 = 0; l1 < 20; l1++) {
                int r = (l1 < 10) ? (40 + l1) : 49;   // pidx
                acc = fmaf(xs[r * FEATN + n], dctS[l1 * 20 + l], acc);
            }
        } else {
            int j = l - 20;
            for (int s2 = 0; s2 < 31; s2++) {
                int mx = n * 31 + s2;                  // flat-reshape semantics
                int s1 = mx / 66, f1 = mx - s1 * 66;
                float inner = 0.f;
#pragma unroll
                for (int l1 = 0; l1 < 20; l1++)
                    inner = fmaf(xs[(s1 + l1) * FEATN + f1], dctS[l1 * 20 + j], inner);
                acc = fmaf(attS[s2], inner, acc);
            }
        }
        ginp[(size_t)b * 2640 + idx] = acc;
    }
}

// ---------------- attmul (gin, 40-wide): T[b] = gin_att @ gi[b] ----------------
__global__ __launch_bounds__(256) void attmul_gin_kernel(
    const float* __restrict__ ginp, const float* __restrict__ attm,
    float* __restrict__ out) {
    __shared__ float gS[2640];
    __shared__ float attS[4356];
    const int b = blockIdx.x, tid = threadIdx.x;
    for (int idx = tid; idx < 2640; idx += 256) gS[idx] = ginp[(size_t)b * 2640 + idx];
    for (int idx = tid; idx < 4356; idx += 256) attS[idx] = attm[idx];
    __syncthreads();
    for (int idx = tid; idx < 2640; idx += 256) {
        int n = idx / 40, l = idx - n * 40;
        float acc = 0.f;
        for (int mm = 0; mm < 66; mm++)
            acc = fmaf(attS[n * 66 + mm], gS[mm * 40 + l], acc);
        out[(size_t)b * 2640 + idx] = acc;
    }
}

// ---------------- attmul (256-wide): out[b] = attm @ S[b] (used once, for gout) ----------------
__global__ __launch_bounds__(256) void attmul_kernel(
    const float* __restrict__ S, const float* __restrict__ attm,
    float* __restrict__ out) {
    __shared__ float Ss[66 * 64];
    __shared__ float attS[4356];
    const int b = blockIdx.x, tid = threadIdx.x;
    for (int idx = tid; idx < 4356; idx += 256) attS[idx] = attm[idx];
    const float* Sb = S + (size_t)b * NNDIM;
    float* ob = out + (size_t)b * NNDIM;
    const int fl = tid & 63, ng = tid >> 6;
    for (int f0 = 0; f0 < 256; f0 += 64) {
        __syncthreads();
        for (int idx = tid; idx < 66 * 64; idx += 256) {
            int mm = idx >> 6, j = idx & 63;
            Ss[idx] = Sb[mm * 256 + f0 + j];
        }
        __syncthreads();
        for (int n = ng; n < 66; n += 4) {
            float acc = 0.f;
            const float* ar = &attS[n * 66];
#pragma unroll 11
            for (int mm = 0; mm < 66; mm++)
                acc = fmaf(ar[mm], Ss[(mm << 6) + fl], acc);
            ob[n * 256 + f0 + fl] = acc;
        }
    }
}

// ---------------- wmul f32 (K=40 gin layer only); W staged in LDS (40 KB) ----------------
template <int K, bool RES>
__global__ __launch_bounds__(256) void wmul_kernel(
    const float* __restrict__ Z, const float* __restrict__ W,
    const float* __restrict__ bias, const float* __restrict__ g,
    const float* __restrict__ beta, const float* __restrict__ res,
    float* __restrict__ out, int rows) {
    __shared__ float As[32 * K];
    __shared__ float Ws[K * HIDN];     // 40*256*4 = 40 KB: kills scattered global W loads
    const int tid = threadIdx.x;
    const size_t row0 = (size_t)blockIdx.x * 32;
    for (int idx = tid; idx < 32 * K; idx += 256) {
        int r = (int)row0 + idx / K;
        As[idx] = (r < rows) ? Z[row0 * K + idx] : 0.f;
    }
    for (int idx = tid; idx < K * (HIDN / 4); idx += 256)
        ((float4*)Ws)[idx] = ((const float4*)W)[idx];
    __syncthreads();
    const int fq = tid & 63, rg = tid >> 6;
    float acc[8][4];
#pragma unroll
    for (int r = 0; r < 8; r++)
#pragma unroll
        for (int c = 0; c < 4; c++) acc[r][c] = 0.f;
    for (int i = 0; i < K; i += 4) {
        float w0[4], w1[4], w2[4], w3[4];
#pragma unroll
        for (int fi = 0; fi < 4; fi++) {
            w0[fi] = Ws[(i + 0) * HIDN + fi * 64 + fq];
            w1[fi] = Ws[(i + 1) * HIDN + fi * 64 + fq];
            w2[fi] = Ws[(i + 2) * HIDN + fi * 64 + fq];
            w3[fi] = Ws[(i + 3) * HIDN + fi * 64 + fq];
        }
#pragma unroll
        for (int rr = 0; rr < 8; rr++) {
            const float4 a = *(const float4*)&As[(rg * 8 + rr) * K + i];
#pragma unroll
            for (int fi = 0; fi < 4; fi++) {
                acc[rr][fi] = fmaf(a.x, w0[fi], acc[rr][fi]);
                acc[rr][fi] = fmaf(a.y, w1[fi], acc[rr][fi]);
                acc[rr][fi] = fmaf(a.z, w2[fi], acc[rr][fi]);
                acc[rr][fi] = fmaf(a.w, w3[fi], acc[rr][fi]);
            }
        }
    }
#pragma unroll
    for (int rr = 0; rr < 8; rr++) {
        int r = (int)row0 + rg * 8 + rr;
        if (r >= rows) continue;
        int n = r % 66;
#pragma unroll
        for (int fi = 0; fi < 4; fi++) {
            int f = fi * 64 + fq;
            float v = (acc[rr][fi] + bias[f]) * INVS;
            v = tanhf(fmaf(v, g[n * 256 + f], beta[n * 256 + f]));
            if (RES) v += res[(size_t)r * 256 + f];
            out[(size_t)r * 256 + f] = v;
        }
    }
}

// ---------------- mega-fused trunk: all 12 GCN layers, 256 threads (4 waves, 4 ct/wave) ----------------
// 78 KB LDS + __launch_bounds__(256, 2): request 2 waves/EU (= 2 blocks/CU) with VGPR
// headroom under 256 (GEMM1 weight prefetch removed, ~-32 VGPRs; at 2 blocks/CU the
// co-resident block's MFMAs hide the weight-load latency instead).
__global__ __launch_bounds__(256, 2) void trunk_kernel(
    float* __restrict__ Y,
    const u16* __restrict__ wpk_hi, const u16* __restrict__ wpk_lo,
    const u16* __restrict__ atA_hi, const u16* __restrict__ atA_lo,
    const float* __restrict__ blk_b,
    const float* __restrict__ bn_g, const float* __restrict__ bn_b) {
    __shared__ u16 Ainh[66 * 264];      // 34848 B
    __shared__ u16 Ainl[66 * 264];
    __shared__ u16 Ubh[4 * 64 * 8];     // 4096 B (per-wave 1 KB stripe, one ct at a time)
    __shared__ u16 Ubl[4 * 64 * 8];
    const int tid = threadIdx.x;
    const int lane = tid & 63, wid = tid >> 6;
    const int m = lane & 15, quad = lane >> 4;
    const int b = blockIdx.x;
    float* Yb = Y + (size_t)b * NNDIM;

    // ---- init: Y0 -> Ain (split) ----
    for (int idx = tid; idx < 8448; idx += 256) {      // 66 rows * 128 col-pairs
        int r = idx >> 7, c2 = (idx & 127) * 2;
        float2 yv = *(const float2*)&Yb[r * 256 + c2];
        u32 h0 = bf_rne(yv.x), h1 = bf_rne(yv.y);
        u32 l0 = bf_rne(yv.x - __uint_as_float(h0 << 16));
        u32 l1 = bf_rne(yv.y - __uint_as_float(h1 << 16));
        *(u32*)&Ainh[r * 264 + c2] = h0 | (h1 << 16);
        *(u32*)&Ainl[r * 264 + c2] = l0 | (l1 << 16);
    }

    // carry = Y0 (f32) at this thread's epilogue positions
    float carry[5][4][4];
#pragma unroll
    for (int rt = 0; rt < 5; rt++)
#pragma unroll
        for (int r = 0; r < 4; r++) {
            int n = rt * 16 + quad * 4 + r;
#pragma unroll
            for (int ct = 0; ct < 4; ct++) {
                int f = wid * 64 + ct * 16 + m;
                carry[rt][r][ct] = (n < 66) ? Yb[n * 256 + f] : 0.f;
            }
        }
    __syncthreads();

    for (int L = 0; L < 12; L++) {
        const u16* wh  = wpk_hi + (size_t)L * 65536;
        const u16* wl  = wpk_lo + (size_t)L * 65536;
        const u16* ath = atA_hi + (size_t)L * 7680;
        const u16* atl = atA_lo + (size_t)L * 7680;
        const float* bias = blk_b + (size_t)L * 256;
        const float* g    = bn_g + (size_t)L * NNDIM;
        const float* beta = bn_b + (size_t)L * NNDIM;
        const bool RES = (L & 1);

        // ---- GEMM1: U = Ain @ W (weight frags loaded per ks; co-resident block hides latency) ----
        f32x4 acc[5][4];
#pragma unroll
        for (int rt = 0; rt < 5; rt++)
#pragma unroll
            for (int ct = 0; ct < 4; ct++) acc[rt][ct] = (f32x4)0.f;

#pragma unroll
        for (int ks = 0; ks < 8; ks++) {
            s16x8 pbh[4], pbl[4];
#pragma unroll
            for (int ct = 0; ct < 4; ct++) {
                size_t boff = ((size_t)(ks * 16 + wid * 4 + ct)) * 512 + lane * 8;
                pbh[ct] = *(const s16x8*)&wh[boff];
                pbl[ct] = *(const s16x8*)&wl[boff];
            }
            s16x8 ahf[5], alf[5];
#pragma unroll
            for (int rt = 0; rt < 4; rt++) {
                int o2 = (rt * 16 + m) * 264 + ks * 32 + quad * 8;
                ahf[rt] = *(const s16x8*)&Ainh[o2];
                alf[rt] = *(const s16x8*)&Ainl[o2];
            }
            {   // rt = 4: rows 64..79; only 64,65 exist (m<2), rest are zeros
                int o2 = ((m < 2) ? (64 + m) : 0) * 264 + ks * 32 + quad * 8;
                s16x8 vh = *(const s16x8*)&Ainh[o2];
                s16x8 vl = *(const s16x8*)&Ainl[o2];
                if (m >= 2) { vh = (s16x8)0; vl = (s16x8)0; }
                ahf[4] = vh; alf[4] = vl;
            }
#pragma unroll
            for (int rt = 0; rt < 5; rt++) {
#pragma unroll
                for (int ct = 0; ct < 4; ct++) {
                    acc[rt][ct] = __builtin_amdgcn_mfma_f32_16x16x32_bf16(
                        ahf[rt], pbh[ct], acc[rt][ct], 0, 0, 0);
                    acc[rt][ct] = __builtin_amdgcn_mfma_f32_16x16x32_bf16(
                        ahf[rt], pbl[ct], acc[rt][ct], 0, 0, 0);
                    acc[rt][ct] = __builtin_amdgcn_mfma_f32_16x16x32_bf16(
                        alf[rt], pbh[ct], acc[rt][ct], 0, 0, 0);
                }
            }
        }

        // ---- GEMM2: Z = att @ U, one (ksf, ct) stripe at a time (intra-wave; no barrier) ----
        f32x4 acc2[5][4];
#pragma unroll
        for (int rt = 0; rt < 5; rt++)
#pragma unroll
            for (int ct = 0; ct < 4; ct++) acc2[rt][ct] = (f32x4)0.f;

#pragma unroll
        for (int ksf = 0; ksf < 3; ksf++) {
            s16x8 afh[5], afl[5];
#pragma unroll
            for (int rt = 0; rt < 5; rt++) {
                size_t aoff = ((size_t)(rt * 3 + ksf)) * 512 + lane * 8;
                afh[rt] = *(const s16x8*)&ath[aoff];
                afl[rt] = *(const s16x8*)&atl[aoff];
            }
#pragma unroll
            for (int ct = 0; ct < 4; ct++) {
                // scatter the two source rt halves of this K-slice into the wave stripe
#pragma unroll
                for (int rr = 0; rr < 2; rr++) {
                    const int rt = ksf * 2 + rr;
                    const int R0 = rt * 16 + quad * 4;         // rt=5 -> rows 80..95 (zeros)
                    const int quadf = (R0 >> 3) & 3;
                    const int jb = R0 & 7;
                    const int base = (wid * 64 + quadf * 16 + m) * 8 + jb;
                    uint2 ph2 = make_uint2(0u, 0u), pl2 = make_uint2(0u, 0u);
                    if (rt <= 4) {
                        float v0 = acc[rt][ct][0], v1 = acc[rt][ct][1];
                        float v2 = acc[rt][ct][2], v3 = acc[rt][ct][3];
                        u32 H0 = bf_rne(v0), H1 = bf_rne(v1), H2 = bf_rne(v2), H3 = bf_rne(v3);
                        u32 L0 = bf_rne(v0 - __uint_as_float(H0 << 16));
                        u32 L1 = bf_rne(v1 - __uint_as_float(H1 << 16));
                        u32 L2 = bf_rne(v2 - __uint_as_float(H2 << 16));
                        u32 L3 = bf_rne(v3 - __uint_as_float(H3 << 16));
                        ph2 = make_uint2(H0 | (H1 << 16), H2 | (H3 << 16));
                        pl2 = make_uint2(L0 | (L1 << 16), L2 | (L3 << 16));
                    }
                    *(uint2*)&Ubh[base] = ph2;
                    *(uint2*)&Ubl[base] = pl2;
                }
                s16x8 ubh = *(const s16x8*)&Ubh[(wid * 64 + lane) * 8];
                s16x8 ubl = *(const s16x8*)&Ubl[(wid * 64 + lane) * 8];
#pragma unroll
                for (int rt = 0; rt < 5; rt++) {
                    acc2[rt][ct] = __builtin_amdgcn_mfma_f32_16x16x32_bf16(
                        afh[rt], ubh, acc2[rt][ct], 0, 0, 0);
                    acc2[rt][ct] = __builtin_amdgcn_mfma_f32_16x16x32_bf16(
                        afh[rt], ubl, acc2[rt][ct], 0, 0, 0);
                    acc2[rt][ct] = __builtin_amdgcn_mfma_f32_16x16x32_bf16(
                        afl[rt], ubh, acc2[rt][ct], 0, 0, 0);
                }
            }
        }

        // ---- epilogue: wait for all waves' Ain reads, then overwrite Ain with next input ----
        __syncthreads();
#pragma unroll
        for (int rt = 0; rt < 5; rt++) {
            const int nb = rt * 16 + quad * 4;
#pragma unroll
            for (int r = 0; r < 4; r++) {
                const int n = nb + r;
                if (n >= 66) continue;
#pragma unroll
                for (int ct = 0; ct < 4; ct++) {
                    const int f = wid * 64 + ct * 16 + m;
                    float v = (acc2[rt][ct][r] + bias[f]) * INVS;
                    v = tanhf(fmaf(v, g[n * 256 + f], beta[n * 256 + f]));
                    if (RES) { v += carry[rt][r][ct]; carry[rt][r][ct] = v; }
                    u32 H = bf_rne(v);
                    u32 Lo = bf_rne(v - __uint_as_float(H << 16));
                    Ainh[n * 264 + f] = (u16)H;
                    Ainl[n * 264 + f] = (u16)Lo;
                    if (L == 11) Yb[n * 256 + f] = v;
                }
            }
        }
        __syncthreads();
    }
}

// ---------------- final: go = (T@gw)[:, :20] + gb + gi[:, :20]; out = go @ dct^T ----------------
__global__ __launch_bounds__(256) void final_kernel(
    const float* __restrict__ T, const float* __restrict__ gw,
    const float* __restrict__ gb, const float* __restrict__ gi,
    const float* __restrict__ dct, float* __restrict__ out) {
    __shared__ float Zt[66 * 64];
    __shared__ float gwS[256 * 20];
    __shared__ float goS[1320];
    __shared__ float dctS[400];
    const int b = blockIdx.x, tid = threadIdx.x;
    for (int idx = tid; idx < 5120; idx += 256) {
        int i = idx / 20, l = idx - i * 20;
        gwS[idx] = gw[i * 40 + l];
    }
    for (int idx = tid; idx < 400; idx += 256) dctS[idx] = dct[idx];
    for (int idx = tid; idx < 1320; idx += 256) {
        int n = idx / 20, l = idx - n * 20;
        goS[idx] = gb[l] + gi[(size_t)b * 2640 + n * 40 + l];
    }
    for (int t = 0; t < 4; t++) {
        __syncthreads();
        for (int idx = tid; idx < 66 * 64; idx += 256) {
            int mm = idx >> 6, j = idx & 63;
            Zt[idx] = T[(size_t)b * NNDIM + mm * 256 + t * 64 + j];
        }
        __syncthreads();
        for (int idx = tid; idx < 1320; idx += 256) {
            int n = idx / 20, l = idx - n * 20;
            float acc = 0.f;
#pragma unroll
            for (int j = 0; j < 64; j++)
                acc = fmaf(Zt[(n << 6) + j], gwS[(t * 64 + j) * 20 + l], acc);
            goS[idx] += acc;
        }
    }
    __syncthreads();
    for (int idx = tid; idx < 1320; idx += 256) {
        int n = idx / 20, mm = idx - n * 20;
        float o = 0.f;
#pragma unroll
        for (int l = 0; l < 20; l++)
            o = fmaf(goS[n * 20 + l], dctS[mm * 20 + l], o);   // idct = dct^T
        out[(size_t)b * 1320 + idx] = o;
    }
}

extern "C" void kernel_launch(void* const* d_in, const int* in_sizes, int n_in,
                              void* d_out, int out_size, void* d_ws, size_t ws_size,
                              hipStream_t stream) {
    const float* x        = (const float*)d_in[0];
    const float* q_w1     = (const float*)d_in[1];
    const float* q_b1     = (const float*)d_in[2];
    const float* q_w2     = (const float*)d_in[3];
    const float* q_b2     = (const float*)d_in[4];
    const float* k_w1     = (const float*)d_in[5];
    const float* k_b1     = (const float*)d_in[6];
    const float* k_w2     = (const float*)d_in[7];
    const float* k_b2     = (const float*)d_in[8];
    const float* gin_w    = (const float*)d_in[9];
    const float* gin_att  = (const float*)d_in[10];
    const float* gin_b    = (const float*)d_in[11];
    const float* bn_in_g  = (const float*)d_in[12];
    const float* bn_in_b  = (const float*)d_in[13];
    const float* blk_w    = (const float*)d_in[14];
    const float* blk_att  = (const float*)d_in[15];
    const float* blk_b    = (const float*)d_in[16];
    const float* blk_bn_g = (const float*)d_in[17];
    const float* blk_bn_b = (const float*)d_in[18];
    const float* gout_w   = (const float*)d_in[19];
    const float* gout_att = (const float*)d_in[20];
    const float* gout_b   = (const float*)d_in[21];
    float* out = (float*)d_out;

    const int B = in_sizes[0] / 3300;

    // Workspace layout
    float* dctb = (float*)d_ws;
    u16* wpk_hi = (u16*)((char*)d_ws + 4096);
    u16* wpk_lo = wpk_hi + 12 * 65536;
    u16* w2q_hi = wpk_lo + 12 * 65536;
    u16* w2q_lo = w2q_hi + 40 * 16 * 512;
    u16* w2k_hi = w2q_lo + 40 * 16 * 512;
    u16* w2k_lo = w2k_hi + 40 * 16 * 512;
    u16* atA_hi = w2k_lo + 40 * 16 * 512;
    u16* atA_lo = atA_hi + 12 * 7680;
    u16* w1q_hi = atA_lo + 12 * 7680;
    u16* w1q_lo = w1q_hi + 13 * 16 * 512;
    u16* w1k_hi = w1q_lo + 13 * 16 * 512;
    u16* w1k_lo = w1k_hi + 13 * 16 * 512;
    const size_t BASE = 4096 + (size_t)2 * 12 * 65536 * 2 + (size_t)4 * 40 * 16 * 512 * 2
                        + (size_t)2 * 12 * 7680 * 2 + (size_t)4 * 13 * 16 * 512 * 2;
    char* R = (char*)d_ws + BASE;
    size_t avail = (ws_size > BASE) ? (ws_size - BASE) : 0;

    // Per-batch floats: Y 16896 + T 16896 + gi 2640 + att 32 + q2 256 = 36720
    const size_t PER_B = 36720ull * 4ull;
    int C = B;
    while (C > 1 && (size_t)C * PER_B > avail) C >>= 1;

    dct_kernel<<<1, 512, 0, stream>>>(dctb);
    pack_w_kernel<<<(12 * 65536) / 256, 256, 0, stream>>>(blk_w, wpk_hi, wpk_lo);
    pack_w2_kernel<<<(40 * 16 * 512) / 256, 256, 0, stream>>>(q_w2, w2q_hi, w2q_lo);
    pack_w2_kernel<<<(40 * 16 * 512) / 256, 256, 0, stream>>>(k_w2, w2k_hi, w2k_lo);
    pack_att_kernel<<<(12 * 7680) / 256, 256, 0, stream>>>(blk_att, atA_hi, atA_lo);
    pack_w1_kernel<<<(13 * 16 * 512) / 256, 256, 0, stream>>>(q_w1, w1q_hi, w1q_lo);
    pack_w1_kernel<<<(13 * 16 * 512) / 256, 256, 0, stream>>>(k_w1, w1k_hi, w1k_lo);

    for (int c0 = 0; c0 < B; c0 += C) {
        const int Cc = (B - c0 < C) ? (B - c0) : C;
        const float* xc = x + (size_t)c0 * 3300;
        float* outc = out + (size_t)c0 * 1320;

        float* Yb  = (float*)R;                      // C*16896
        float* Tb  = Yb + (size_t)C * 16896;         // C*16896
        float* gib = Tb + (size_t)C * 16896;         // C*2640
        float* ab  = gib + (size_t)C * 2640;         // C*32
        float* q2b = ab + (size_t)C * 32;            // C*256
        // conv temporaries aliased into dead zones:
        float* k1b = Yb;                             // C*8960  (dead after conv2_mfma)
        float* k2b = Tb;                             // C*7936  (dead after att)
        float* q1b = gib;                            // C*1280  (dead before gi written)

        const int c1q = (Cc * 5 + 63) / 64, c1k = (Cc * 35 + 63) / 64;
        conv1_mfma_kernel<<<c1q + c1k, 256, 0, stream>>>(
            xc, w1q_hi, w1q_lo, w1k_hi, w1k_lo, q_b1, k_b1, q1b, k1b, Cc, c1q);
        const int c2q = (Cc + 63) / 64, c2k = (Cc * 31 + 63) / 64;
        conv2_mfma_kernel<<<c2q + c2k, 256, 0, stream>>>(
            q1b, k1b, w2q_hi, w2q_lo, w2k_hi, w2k_lo, q_b2, k_b2, q2b, k2b, Cc, c2q);
        att_kernel<<<Cc, 64, 0, stream>>>(q2b, k2b, ab);
        gcn_inp_kernel<<<Cc, 256, 0, stream>>>(xc, ab, dctb, gib);

        const int rows = Cc * FEATN;
        const int g32 = (rows + 31) / 32;

        // gin: T = gin_att @ gi (40-wide, flat); Y = tanh(bn(T @ gin_w + gin_b))
        attmul_gin_kernel<<<Cc, 256, 0, stream>>>(gib, gin_att, Tb);
        wmul_kernel<40, false><<<g32, 256, 0, stream>>>(Tb, gin_w, gin_b,
                                                        bn_in_g, bn_in_b, nullptr, Yb, rows);
        // all 12 residual layers in one resident kernel (78 KB LDS, 2 waves/EU requested)
        trunk_kernel<<<Cc, 256, 0, stream>>>(Yb, wpk_hi, wpk_lo, atA_hi, atA_lo,
                                             blk_b, blk_bn_g, blk_bn_b);
        // gout + idct
        attmul_kernel<<<Cc, 256, 0, stream>>>(Yb, gout_att, Tb);
        final_kernel<<<Cc, 256, 0, stream>>>(Tb, gout_w, gout_b, gib, dctb, outc);
    }
}

// Round 13
// 4576.901 us; speedup vs baseline: 1.0095x; 1.0095x over previous
//
#include <hip/hip_runtime.h>
#include <math.h>

typedef unsigned short u16;
typedef unsigned int u32;

#define FEATN 66
#define HIDN 256
#define NNDIM 16896      // 66*256
#define INVS 0.9999950000374998f
#ifndef M_PI
#define M_PI 3.14159265358979323846
#endif

typedef __attribute__((ext_vector_type(4))) float f32x4;
typedef __attribute__((ext_vector_type(2))) float f32x2;
typedef __attribute__((ext_vector_type(8))) short s16x8;

__device__ __forceinline__ u32 bf_rne(float x) {
    u32 i = __float_as_uint(x);
    return (i + 0x7fffu + ((i >> 16) & 1u)) >> 16;
}

// ---------------- DCT matrix (parallel build; orthonormal: inv = transpose) ----------------
__global__ void dct_kernel(float* __restrict__ dct) {
    int t = threadIdx.x;
    if (t < 400) {
        int k = t / 20, i = t % 20;
        double w = (k == 0) ? sqrt(1.0 / 20.0) : sqrt(2.0 / 20.0);
        dct[t] = (float)(w * cos(M_PI * (i + 0.5) * k / 20.0));
    }
}

// ---------------- pack blk_w into split-bf16 MFMA B-fragment layout ----------------
// index within layer: (ks*16 + ct)*512 + lane*8 + j ; value = W[k=ks*32+(lane>>4)*8+j][n=ct*16+(lane&15)]
__global__ __launch_bounds__(256) void pack_w_kernel(
    const float* __restrict__ blk_w, u16* __restrict__ wh, u16* __restrict__ wl) {
    int gid = blockIdx.x * 256 + threadIdx.x;
    if (gid >= 12 * 65536) return;
    int layer = gid >> 16, rmd = gid & 65535;
    int ks = rmd >> 13;
    int r2 = rmd & 8191;
    int ct = r2 >> 9;
    int r3 = r2 & 511;
    int lane = r3 >> 3, j = r3 & 7;
    int k = ks * 32 + (lane >> 4) * 8 + j;
    int n = ct * 16 + (lane & 15);
    float v = blk_w[(size_t)layer * 65536 + k * 256 + n];
    u32 rhi = bf_rne(v);
    float hif = __uint_as_float(rhi << 16);
    u32 rlo = bf_rne(v - hif);
    wh[gid] = (u16)rhi;
    wl[gid] = (u16)rlo;
}

// ---------------- pack conv2 weights, K reordered t-major: k' = t*256 + h ----------------
__global__ __launch_bounds__(256) void pack_w2_kernel(
    const float* __restrict__ w2, u16* __restrict__ wh, u16* __restrict__ wl) {
    int gid = blockIdx.x * 256 + threadIdx.x;
    if (gid >= 40 * 16 * 512) return;
    int ks = gid >> 13;
    int r2 = gid & 8191;
    int ct = r2 >> 9;
    int r3 = r2 & 511;
    int lane = r3 >> 3, j = r3 & 7;
    int k = ks * 32 + (lane >> 4) * 8 + j;
    int n = ct * 16 + (lane & 15);
    int h = k & 255, t = k >> 8;
    float v = w2[(size_t)n * 1280 + h * 5 + t];
    u32 rhi = bf_rne(v);
    float hif = __uint_as_float(rhi << 16);
    u32 rlo = bf_rne(v - hif);
    wh[gid] = (u16)rhi;
    wl[gid] = (u16)rlo;
}

// ---------------- pack conv1 weights, K reordered t-major: k' = t*66 + f (pad to 416) ----------------
__global__ __launch_bounds__(256) void pack_w1_kernel(
    const float* __restrict__ w1, u16* __restrict__ wh, u16* __restrict__ wl) {
    int gid = blockIdx.x * 256 + threadIdx.x;
    if (gid >= 13 * 16 * 512) return;
    int ks = gid >> 13;
    int r2 = gid & 8191;
    int ct = r2 >> 9;
    int r3 = r2 & 511;
    int lane = r3 >> 3, j = r3 & 7;
    int k = ks * 32 + (lane >> 4) * 8 + j;
    int n = ct * 16 + (lane & 15);
    float v = 0.f;
    if (k < 396) {
        int f = k % 66, t = k / 66;
        v = w1[(size_t)n * 396 + f * 6 + t];
    }
    u32 rhi = bf_rne(v);
    float hif = __uint_as_float(rhi << 16);
    u32 rlo = bf_rne(v - hif);
    wh[gid] = (u16)rhi;
    wl[gid] = (u16)rlo;
}

// ---------------- pack blk_att into split-bf16 MFMA A-fragment layout ----------------
__global__ __launch_bounds__(256) void pack_att_kernel(
    const float* __restrict__ blk_att, u16* __restrict__ ah, u16* __restrict__ al) {
    int gid = blockIdx.x * 256 + threadIdx.x;
    if (gid >= 12 * 7680) return;
    int layer = gid / 7680, rem = gid % 7680;
    int rt = rem / 1536, rem2 = rem % 1536;
    int ks = rem2 / 512, r3 = rem2 % 512;
    int lane = r3 >> 3, j = r3 & 7;
    int n = rt * 16 + (lane & 15);
    int k = ks * 32 + (lane >> 4) * 8 + j;
    float v = (n < 66 && k < 66) ? blk_att[(size_t)layer * 4356 + n * 66 + k] : 0.f;
    u32 rhi = bf_rne(v);
    float hif = __uint_as_float(rhi << 16);
    u32 rlo = bf_rne(v - hif);
    ah[gid] = (u16)rhi;
    al[gid] = (u16)rlo;
}

// ---------------- pack bn g/beta into trunk-epilogue order: out[(L*80+i)*256+tid] ----------------
// i = (rt*4+r)*4+ct ; tid = wid*64+quad*16+m ; value = bn[L][n=rt*16+quad*4+r][f=wid*64+ct*16+m]
// (zeros for n>=66 — epilogue guard never reads them). Makes epilogue loads wave-coalesced.
__global__ __launch_bounds__(256) void pack_bn_kernel(
    const float* __restrict__ bn, float* __restrict__ outp) {
    int gid = blockIdx.x * 256 + threadIdx.x;
    if (gid >= 12 * 80 * 256) return;
    int tid = gid & 255;
    int rem = gid >> 8;
    int L = rem / 80, i = rem - L * 80;
    int ct = i & 3, rr = (i >> 2) & 3, rt = i >> 4;
    int lane = tid & 63, wid = tid >> 6;
    int mq = lane & 15, quad = lane >> 4;
    int n = rt * 16 + quad * 4 + rr;
    int f = wid * 64 + ct * 16 + mq;
    outp[gid] = (n < 66) ? bn[(size_t)L * NNDIM + n * 256 + f] : 0.f;
}

// ---------------- conv1 as MFMA GEMM (split-bf16), q+k merged: N=256, K=396(pad 416) ----------------
__global__ __launch_bounds__(256, 1) void conv1_mfma_kernel(
    const float* __restrict__ x,
    const u16* __restrict__ whq, const u16* __restrict__ wlq,
    const u16* __restrict__ whk, const u16* __restrict__ wlk,
    const float* __restrict__ bq, const float* __restrict__ bk,
    float* __restrict__ q1, float* __restrict__ k1, int Cc, int nbq) {
    __shared__ u16 Ah[64 * 136];
    __shared__ u16 Al[64 * 136];
    const int tid = threadIdx.x;
    const int lane = tid & 63, wid = tid >> 6;
    const int m = lane & 15, quad = lane >> 4;
    const bool isq = ((int)blockIdx.x < nbq);
    const int bid = isq ? (int)blockIdx.x : ((int)blockIdx.x - nbq);
    const int rows = isq ? Cc * 5 : Cc * 35;
    const int row0 = bid * 64;
    const u16* wh = isq ? whq : whk;
    const u16* wl = isq ? wlq : wlk;
    const float* bias = isq ? bq : bk;
    float* out = isq ? q1 : k1;

    const int cq = tid & 31;
    const int r0t = (tid >> 5) * 8;
    int rbc[8]; bool vld[8];
#pragma unroll
    for (int s = 0; s < 8; s++) {
        int grow = row0 + r0t + s;
        int rbv;
        if (isq) { int bb = grow / 5;  rbv = bb * 3300 + 2640 + (grow - bb * 5) * 66; }
        else     { int bb = grow / 35; rbv = bb * 3300 + (grow - bb * 35) * 66; }
        vld[s] = (grow < rows);
        rbc[s] = vld[s] ? rbv : 0;
    }

    f32x4 acc[4][4];
#pragma unroll
    for (int rt = 0; rt < 4; rt++)
#pragma unroll
        for (int ct = 0; ct < 4; ct++) acc[rt][ct] = (f32x4)0.f;

    f32x2 ldA[16], ldB[16];

    auto LOADP = [&](f32x2* dst, int ph) {
        const int off = ph * 128 + cq * 4;
        const bool kok = (off < 396);
        const int o = kok ? off : 0;
#pragma unroll
        for (int s = 0; s < 8; s++) {
            const float* p = x + rbc[s] + o;
            dst[2 * s]     = *(const f32x2*)p;
            dst[2 * s + 1] = *(const f32x2*)(p + 2);
        }
    };
    auto STOREP = [&](const f32x2* src, int ph) {
        const bool kok = (ph * 128 + cq * 4) < 396;
#pragma unroll
        for (int s = 0; s < 8; s++) {
            float v0 = src[2 * s][0], v1 = src[2 * s][1];
            float v2 = src[2 * s + 1][0], v3 = src[2 * s + 1][1];
            if (!vld[s] || !kok) { v0 = v1 = v2 = v3 = 0.f; }
            u32 H0 = bf_rne(v0), H1 = bf_rne(v1), H2 = bf_rne(v2), H3 = bf_rne(v3);
            u32 L0 = bf_rne(v0 - __uint_as_float(H0 << 16));
            u32 L1 = bf_rne(v1 - __uint_as_float(H1 << 16));
            u32 L2 = bf_rne(v2 - __uint_as_float(H2 << 16));
            u32 L3 = bf_rne(v3 - __uint_as_float(H3 << 16));
            int o = (r0t + s) * 136 + cq * 4;
            *(uint2*)&Ah[o] = make_uint2(H0 | (H1 << 16), H2 | (H3 << 16));
            *(uint2*)&Al[o] = make_uint2(L0 | (L1 << 16), L2 | (L3 << 16));
        }
    };
    auto MFMAP = [&](int ph) {
#pragma unroll
        for (int ks = 0; ks < 4; ks++) {
            const int ksg = ph * 4 + ks;
            if (ksg >= 13) break;
            s16x8 ahf[4], alf[4], bhf[4], blf[4];
#pragma unroll
            for (int rt = 0; rt < 4; rt++) {
                int o2 = (rt * 16 + m) * 136 + ks * 32 + quad * 8;
                ahf[rt] = *(const s16x8*)&Ah[o2];
                alf[rt] = *(const s16x8*)&Al[o2];
            }
#pragma unroll
            for (int ct = 0; ct < 4; ct++) {
                size_t boff = ((size_t)(ksg * 16 + wid * 4 + ct)) * 512 + lane * 8;
                bhf[ct] = *(const s16x8*)&wh[boff];
                blf[ct] = *(const s16x8*)&wl[boff];
            }
#pragma unroll
            for (int rt = 0; rt < 4; rt++) {
#pragma unroll
                for (int ct = 0; ct < 4; ct++) {
                    acc[rt][ct] = __builtin_amdgcn_mfma_f32_16x16x32_bf16(
                        ahf[rt], bhf[ct], acc[rt][ct], 0, 0, 0);
                    acc[rt][ct] = __builtin_amdgcn_mfma_f32_16x16x32_bf16(
                        ahf[rt], blf[ct], acc[rt][ct], 0, 0, 0);
                    acc[rt][ct] = __builtin_amdgcn_mfma_f32_16x16x32_bf16(
                        alf[rt], bhf[ct], acc[rt][ct], 0, 0, 0);
                }
            }
        }
    };

    LOADP(ldA, 0);
    for (int ph = 0; ph < 4; ph += 2) {
        __syncthreads();
        STOREP(ldA, ph);
        LOADP(ldB, ph + 1);
        __syncthreads();
        MFMAP(ph);
        __syncthreads();
        STOREP(ldB, ph + 1);
        if (ph + 2 < 4) LOADP(ldA, ph + 2);
        __syncthreads();
        MFMAP(ph + 1);
    }

#pragma unroll
    for (int rt = 0; rt < 4; rt++) {
        int rb2 = row0 + rt * 16 + quad * 4;
#pragma unroll
        for (int r = 0; r < 4; r++) {
            int grow = rb2 + r;
            if (grow >= rows) continue;
#pragma unroll
            for (int ct = 0; ct < 4; ct++) {
                int f = wid * 64 + ct * 16 + m;
                float v = acc[rt][ct][r] + bias[f];
                out[(size_t)grow * 256 + f] = fmaxf(v, 0.f);
            }
        }
    }
}

// ---------------- conv2 as MFMA GEMM (split-bf16), q+k merged: N=256, K=1280 ----------------
__global__ __launch_bounds__(256, 1) void conv2_mfma_kernel(
    const float* __restrict__ Aq, const float* __restrict__ Ak,
    const u16* __restrict__ whq, const u16* __restrict__ wlq,
    const u16* __restrict__ whk, const u16* __restrict__ wlk,
    const float* __restrict__ bq, const float* __restrict__ bk,
    float* __restrict__ q2, float* __restrict__ k2, int Cc, int nbq) {
    __shared__ u16 Ah[64 * 136];
    __shared__ u16 Al[64 * 136];
    const int tid = threadIdx.x;
    const int lane = tid & 63, wid = tid >> 6;
    const int m = lane & 15, quad = lane >> 4;
    const bool isq = ((int)blockIdx.x < nbq);
    const int bid = isq ? (int)blockIdx.x : ((int)blockIdx.x - nbq);
    const int rows = isq ? Cc : Cc * 31;
    const int row0 = bid * 64;
    const float* Asrc = isq ? Aq : Ak;
    const u16* wh = isq ? whq : whk;
    const u16* wl = isq ? wlq : wlk;
    const float* bias = isq ? bq : bk;
    float* out = isq ? q2 : k2;

    const int cq = tid & 31;
    const int r0t = (tid >> 5) * 8;
    int rbc[8]; bool vld[8];
#pragma unroll
    for (int s = 0; s < 8; s++) {
        int grow = row0 + r0t + s;
        int rbv;
        if (isq) rbv = grow * 1280;
        else { int bb = grow / 31; rbv = bb * 8960 + (grow - bb * 31) * 256; }
        vld[s] = (grow < rows);
        rbc[s] = vld[s] ? rbv : 0;
    }

    f32x4 acc[4][4];
#pragma unroll
    for (int rt = 0; rt < 4; rt++)
#pragma unroll
        for (int ct = 0; ct < 4; ct++) acc[rt][ct] = (f32x4)0.f;

    f32x4 ldA[8], ldB[8];

    auto LOADP = [&](f32x4* dst, int ph) {
        const int off = ph * 128 + cq * 4;
#pragma unroll
        for (int s = 0; s < 8; s++)
            dst[s] = *(const f32x4*)(Asrc + rbc[s] + off);
    };
    auto STOREP = [&](const f32x4* src) {
#pragma unroll
        for (int s = 0; s < 8; s++) {
            f32x4 v = src[s];
            if (!vld[s]) v = (f32x4)0.f;
            u32 H0 = bf_rne(v[0]), H1 = bf_rne(v[1]), H2 = bf_rne(v[2]), H3 = bf_rne(v[3]);
            u32 L0 = bf_rne(v[0] - __uint_as_float(H0 << 16));
            u32 L1 = bf_rne(v[1] - __uint_as_float(H1 << 16));
            u32 L2 = bf_rne(v[2] - __uint_as_float(H2 << 16));
            u32 L3 = bf_rne(v[3] - __uint_as_float(H3 << 16));
            int o = (r0t + s) * 136 + cq * 4;
            *(uint2*)&Ah[o] = make_uint2(H0 | (H1 << 16), H2 | (H3 << 16));
            *(uint2*)&Al[o] = make_uint2(L0 | (L1 << 16), L2 | (L3 << 16));
        }
    };
    auto MFMAP = [&](int ph) {
#pragma unroll
        for (int ks = 0; ks < 4; ks++) {
            const int ksg = ph * 4 + ks;
            s16x8 ahf[4], alf[4], bhf[4], blf[4];
#pragma unroll
            for (int rt = 0; rt < 4; rt++) {
                int o2 = (rt * 16 + m) * 136 + ks * 32 + quad * 8;
                ahf[rt] = *(const s16x8*)&Ah[o2];
                alf[rt] = *(const s16x8*)&Al[o2];
            }
#pragma unroll
            for (int ct = 0; ct < 4; ct++) {
                size_t boff = ((size_t)(ksg * 16 + wid * 4 + ct)) * 512 + lane * 8;
                bhf[ct] = *(const s16x8*)&wh[boff];
                blf[ct] = *(const s16x8*)&wl[boff];
            }
#pragma unroll
            for (int rt = 0; rt < 4; rt++) {
#pragma unroll
                for (int ct = 0; ct < 4; ct++) {
                    acc[rt][ct] = __builtin_amdgcn_mfma_f32_16x16x32_bf16(
                        ahf[rt], bhf[ct], acc[rt][ct], 0, 0, 0);
                    acc[rt][ct] = __builtin_amdgcn_mfma_f32_16x16x32_bf16(
                        ahf[rt], blf[ct], acc[rt][ct], 0, 0, 0);
                    acc[rt][ct] = __builtin_amdgcn_mfma_f32_16x16x32_bf16(
                        alf[rt], bhf[ct], acc[rt][ct], 0, 0, 0);
                }
            }
        }
    };

    LOADP(ldA, 0);
    for (int ph = 0; ph < 10; ph += 2) {
        __syncthreads();
        STOREP(ldA);
        LOADP(ldB, ph + 1);
        __syncthreads();
        MFMAP(ph);
        __syncthreads();
        STOREP(ldB);
        if (ph + 2 < 10) LOADP(ldA, ph + 2);
        __syncthreads();
        MFMAP(ph + 1);
    }

#pragma unroll
    for (int rt = 0; rt < 4; rt++) {
        int rb2 = row0 + rt * 16 + quad * 4;
#pragma unroll
        for (int r = 0; r < 4; r++) {
            int grow = rb2 + r;
            if (grow >= rows) continue;
#pragma unroll
            for (int ct = 0; ct < 4; ct++) {
                int f = wid * 64 + ct * 16 + m;
                float v = acc[rt][ct][r] + bias[f];
                out[(size_t)grow * 256 + f] = fmaxf(v, 0.f);
            }
        }
    }
}

// ---------------- attention weights (one wave per batch); k2 layout [b][s][c] ----------------
__global__ void att_kernel(const float* __restrict__ q2, const float* __restrict__ k2,
                           float* __restrict__ att) {
    __shared__ float q2s[256];
    const int b = blockIdx.x, tid = threadIdx.x;
    for (int i = tid; i < 256; i += 64) q2s[i] = q2[(size_t)b * 256 + i];
    __syncthreads();
    float sc = 0.f;
    if (tid < 31) {
        const f32x4* kp = (const f32x4*)(k2 + (size_t)b * 7936 + tid * 256);
        for (int c = 0; c < 64; c++) {
            f32x4 kv = kp[c];
            sc = fmaf(q2s[c * 4 + 0], kv[0], sc);
            sc = fmaf(q2s[c * 4 + 1], kv[1], sc);
            sc = fmaf(q2s[c * 4 + 2], kv[2], sc);
            sc = fmaf(q2s[c * 4 + 3], kv[3], sc);
        }
    }
    float tot = sc;
#pragma unroll
    for (int off = 1; off < 64; off <<= 1) tot += __shfl_xor(tot, off);
    if (tid < 31) att[(size_t)b * 32 + tid] = (tot != 0.f) ? (sc / tot) : 0.f;
}

// ---------------- gcn_inp = concat(padded_query, att_final) ----------------
__global__ __launch_bounds__(256) void gcn_inp_kernel(
    const float* __restrict__ x, const float* __restrict__ att,
    const float* __restrict__ dct, float* __restrict__ ginp) {
    __shared__ float xs[3300];
    __shared__ float dctS[400];
    __shared__ float attS[31];
    const int b = blockIdx.x, tid = threadIdx.x;
    const float* xb = x + (size_t)b * 3300;
    for (int idx = tid; idx < 3300; idx += 256) xs[idx] = xb[idx];
    for (int idx = tid; idx < 400; idx += 256) dctS[idx] = dct[idx];
    if (tid < 31) attS[tid] = att[(size_t)b * 32 + tid];
    __syncthreads();
    for (int idx = tid; idx < 2640; idx += 256) {
        int n = idx / 40, l = idx - n * 40;
        float acc = 0.f;
        if (l < 20) {
#pragma unroll
            for (int l1 = 0; l1 < 20; l1++) {
                int r = (l1 < 10) ? (40 + l1) : 49;   // pidx
                acc = fmaf(xs[r * FEATN + n], dctS[l1 * 20 + l], acc);
            }
        } else {
            int j = l - 20;
            for (int s2 = 0; s2 < 31; s2++) {
                int mx = n * 31 + s2;                  // flat-reshape semantics
                int s1 = mx / 66, f1 = mx - s1 * 66;
                float inner = 0.f;
#pragma unroll
                for (int l1 = 0; l1 < 20; l1++)
                    inner = fmaf(xs[(s1 + l1) * FEATN + f1], dctS[l1 * 20 + j], inner);
                acc = fmaf(attS[s2], inner, acc);
            }
        }
        ginp[(size_t)b * 2640 + idx] = acc;
    }
}

// ---------------- attmul (gin, 40-wide): T[b] = gin_att @ gi[b] ----------------
__global__ __launch_bounds__(256) void attmul_gin_kernel(
    const float* __restrict__ ginp, const float* __restrict__ attm,
    float* __restrict__ out) {
    __shared__ float gS[2640];
    __shared__ float attS[4356];
    const int b = blockIdx.x, tid = threadIdx.x;
    for (int idx = tid; idx < 2640; idx += 256) gS[idx] = ginp[(size_t)b * 2640 + idx];
    for (int idx = tid; idx < 4356; idx += 256) attS[idx] = attm[idx];
    __syncthreads();
    for (int idx = tid; idx < 2640; idx += 256) {
        int n = idx / 40, l = idx - n * 40;
        float acc = 0.f;
        for (int mm = 0; mm < 66; mm++)
            acc = fmaf(attS[n * 66 + mm], gS[mm * 40 + l], acc);
        out[(size_t)b * 2640 + idx] = acc;
    }
}

// ---------------- attmul (256-wide): out[b] = attm @ S[b] (used once, for gout) ----------------
__global__ __launch_bounds__(256) void attmul_kernel(
    const float* __restrict__ S, const float* __restrict__ attm,
    float* __restrict__ out) {
    __shared__ float Ss[66 * 64];
    __shared__ float attS[4356];
    const int b = blockIdx.x, tid = threadIdx.x;
    for (int idx = tid; idx < 4356; idx += 256) attS[idx] = attm[idx];
    const float* Sb = S + (size_t)b * NNDIM;
    float* ob = out + (size_t)b * NNDIM;
    const int fl = tid & 63, ng = tid >> 6;
    for (int f0 = 0; f0 < 256; f0 += 64) {
        __syncthreads();
        for (int idx = tid; idx < 66 * 64; idx += 256) {
            int mm = idx >> 6, j = idx & 63;
            Ss[idx] = Sb[mm * 256 + f0 + j];
        }
        __syncthreads();
        for (int n = ng; n < 66; n += 4) {
            float acc = 0.f;
            const float* ar = &attS[n * 66];
#pragma unroll 11
            for (int mm = 0; mm < 66; mm++)
                acc = fmaf(ar[mm], Ss[(mm << 6) + fl], acc);
            ob[n * 256 + f0 + fl] = acc;
        }
    }
}

// ---------------- wmul f32 (K=40 gin layer only); W staged in LDS (40 KB) ----------------
template <int K, bool RES>
__global__ __launch_bounds__(256) void wmul_kernel(
    const float* __restrict__ Z, const float* __restrict__ W,
    const float* __restrict__ bias, const float* __restrict__ g,
    const float* __restrict__ beta, const float* __restrict__ res,
    float* __restrict__ out, int rows) {
    __shared__ float As[32 * K];
    __shared__ float Ws[K * HIDN];     // 40*256*4 = 40 KB: kills scattered global W loads
    const int tid = threadIdx.x;
    const size_t row0 = (size_t)blockIdx.x * 32;
    for (int idx = tid; idx < 32 * K; idx += 256) {
        int r = (int)row0 + idx / K;
        As[idx] = (r < rows) ? Z[row0 * K + idx] : 0.f;
    }
    for (int idx = tid; idx < K * (HIDN / 4); idx += 256)
        ((float4*)Ws)[idx] = ((const float4*)W)[idx];
    __syncthreads();
    const int fq = tid & 63, rg = tid >> 6;
    float acc[8][4];
#pragma unroll
    for (int r = 0; r < 8; r++)
#pragma unroll
        for (int c = 0; c < 4; c++) acc[r][c] = 0.f;
    for (int i = 0; i < K; i += 4) {
        float w0[4], w1[4], w2[4], w3[4];
#pragma unroll
        for (int fi = 0; fi < 4; fi++) {
            w0[fi] = Ws[(i + 0) * HIDN + fi * 64 + fq];
            w1[fi] = Ws[(i + 1) * HIDN + fi * 64 + fq];
            w2[fi] = Ws[(i + 2) * HIDN + fi * 64 + fq];
            w3[fi] = Ws[(i + 3) * HIDN + fi * 64 + fq];
        }
#pragma unroll
        for (int rr = 0; rr < 8; rr++) {
            const float4 a = *(const float4*)&As[(rg * 8 + rr) * K + i];
#pragma unroll
            for (int fi = 0; fi < 4; fi++) {
                acc[rr][fi] = fmaf(a.x, w0[fi], acc[rr][fi]);
                acc[rr][fi] = fmaf(a.y, w1[fi], acc[rr][fi]);
                acc[rr][fi] = fmaf(a.z, w2[fi], acc[rr][fi]);
                acc[rr][fi] = fmaf(a.w, w3[fi], acc[rr][fi]);
            }
        }
    }
#pragma unroll
    for (int rr = 0; rr < 8; rr++) {
        int r = (int)row0 + rg * 8 + rr;
        if (r >= rows) continue;
        int n = r % 66;
#pragma unroll
        for (int fi = 0; fi < 4; fi++) {
            int f = fi * 64 + fq;
            float v = (acc[rr][fi] + bias[f]) * INVS;
            v = tanhf(fmaf(v, g[n * 256 + f], beta[n * 256 + f]));
            if (RES) v += res[(size_t)r * 256 + f];
            out[(size_t)r * 256 + f] = v;
        }
    }
}

// ---------------- mega-fused trunk: all 12 GCN layers, 256 threads (4 waves, 4 ct/wave) ----------------
// The ONLY spill-free configuration (R10: VGPR 256, FETCH = one Y pass; every >1-blk/CU
// config caps VGPR <=128 and spills 2+ GB/dispatch — R7/R8/R9/R12). Epilogue BN loads now
// read pre-packed coalesced arrays (pack_bn_kernel) instead of 1KB-stride gathers.
__global__ __launch_bounds__(256, 1) void trunk_kernel(
    float* __restrict__ Y,
    const u16* __restrict__ wpk_hi, const u16* __restrict__ wpk_lo,
    const u16* __restrict__ atA_hi, const u16* __restrict__ atA_lo,
    const float* __restrict__ blk_b,
    const float* __restrict__ bn_gp, const float* __restrict__ bn_bp) {
    __shared__ u16 Ainh[80 * 264];      // 42240 B
    __shared__ u16 Ainl[80 * 264];
    __shared__ u16 Ubh[16 * 64 * 8];    // 16384 B (one ks-slice)
    __shared__ u16 Ubl[16 * 64 * 8];
    const int tid = threadIdx.x;
    const int lane = tid & 63, wid = tid >> 6;
    const int m = lane & 15, quad = lane >> 4;
    const int b = blockIdx.x;
    float* Yb = Y + (size_t)b * NNDIM;

    // ---- init: Y0 -> Ain (split), zero pad rows + Ub ----
    for (int idx = tid; idx < 8448; idx += 256) {      // 66 rows * 128 col-pairs
        int r = idx >> 7, c2 = (idx & 127) * 2;
        float2 yv = *(const float2*)&Yb[r * 256 + c2];
        u32 h0 = bf_rne(yv.x), h1 = bf_rne(yv.y);
        u32 l0 = bf_rne(yv.x - __uint_as_float(h0 << 16));
        u32 l1 = bf_rne(yv.y - __uint_as_float(h1 << 16));
        *(u32*)&Ainh[r * 264 + c2] = h0 | (h1 << 16);
        *(u32*)&Ainl[r * 264 + c2] = l0 | (l1 << 16);
    }
    for (int idx = tid; idx < 14 * 264; idx += 256) {
        Ainh[66 * 264 + idx] = 0; Ainl[66 * 264 + idx] = 0;
    }
    for (int idx = tid; idx < 8192; idx += 256) { Ubh[idx] = 0; Ubl[idx] = 0; }

    // carry = Y0 (f32) at this thread's epilogue positions
    float carry[5][4][4];
#pragma unroll
    for (int rt = 0; rt < 5; rt++)
#pragma unroll
        for (int r = 0; r < 4; r++) {
            int n = rt * 16 + quad * 4 + r;
#pragma unroll
            for (int ct = 0; ct < 4; ct++) {
                int f = wid * 64 + ct * 16 + m;
                carry[rt][r][ct] = (n < 66) ? Yb[n * 256 + f] : 0.f;
            }
        }
    __syncthreads();

    for (int L = 0; L < 12; L++) {
        const u16* wh  = wpk_hi + (size_t)L * 65536;
        const u16* wl  = wpk_lo + (size_t)L * 65536;
        const u16* ath = atA_hi + (size_t)L * 7680;
        const u16* atl = atA_lo + (size_t)L * 7680;
        const float* bias = blk_b + (size_t)L * 256;
        const float* gp   = bn_gp + (size_t)L * 80 * 256;
        const float* bp   = bn_bp + (size_t)L * 80 * 256;
        const bool RES = (L & 1);

        // ---- GEMM1: U = Ain @ W ; weight frags prefetched 1 ks ahead ----
        f32x4 acc[5][4];
#pragma unroll
        for (int rt = 0; rt < 5; rt++)
#pragma unroll
            for (int ct = 0; ct < 4; ct++) acc[rt][ct] = (f32x4)0.f;

        s16x8 pbh[4], pbl[4];
#pragma unroll
        for (int ct = 0; ct < 4; ct++) {
            size_t boff = ((size_t)(wid * 4 + ct)) * 512 + lane * 8;
            pbh[ct] = *(const s16x8*)&wh[boff];
            pbl[ct] = *(const s16x8*)&wl[boff];
        }
#pragma unroll
        for (int ks = 0; ks < 8; ks++) {
            s16x8 nbh[4], nbl[4];
            if (ks < 7) {
#pragma unroll
                for (int ct = 0; ct < 4; ct++) {
                    size_t boff = ((size_t)((ks + 1) * 16 + wid * 4 + ct)) * 512 + lane * 8;
                    nbh[ct] = *(const s16x8*)&wh[boff];
                    nbl[ct] = *(const s16x8*)&wl[boff];
                }
            }
            s16x8 ahf[5], alf[5];
#pragma unroll
            for (int rt = 0; rt < 5; rt++) {
                int o2 = (rt * 16 + m) * 264 + ks * 32 + quad * 8;
                ahf[rt] = *(const s16x8*)&Ainh[o2];
                alf[rt] = *(const s16x8*)&Ainl[o2];
            }
#pragma unroll
            for (int rt = 0; rt < 5; rt++) {
#pragma unroll
                for (int ct = 0; ct < 4; ct++) {
                    acc[rt][ct] = __builtin_amdgcn_mfma_f32_16x16x32_bf16(
                        ahf[rt], pbh[ct], acc[rt][ct], 0, 0, 0);
                    acc[rt][ct] = __builtin_amdgcn_mfma_f32_16x16x32_bf16(
                        ahf[rt], pbl[ct], acc[rt][ct], 0, 0, 0);
                    acc[rt][ct] = __builtin_amdgcn_mfma_f32_16x16x32_bf16(
                        alf[rt], pbh[ct], acc[rt][ct], 0, 0, 0);
                }
            }
            if (ks < 7) {
#pragma unroll
                for (int ct = 0; ct < 4; ct++) { pbh[ct] = nbh[ct]; pbl[ct] = nbl[ct]; }
            }
        }

        // ---- GEMM2: Z = att @ U, ks-slice at a time (scatter is intra-wave; no barrier) ----
        f32x4 acc2[5][4];
#pragma unroll
        for (int rt = 0; rt < 5; rt++)
#pragma unroll
            for (int ct = 0; ct < 4; ct++) acc2[rt][ct] = (f32x4)0.f;

#pragma unroll
        for (int ksf = 0; ksf < 3; ksf++) {
            s16x8 afh[5], afl[5];
#pragma unroll
            for (int rt = 0; rt < 5; rt++) {
                size_t aoff = ((size_t)(rt * 3 + ksf)) * 512 + lane * 8;
                afh[rt] = *(const s16x8*)&ath[aoff];
                afl[rt] = *(const s16x8*)&atl[aoff];
            }
            // scatter acc rows for this ks-slice (ksf0: rt0,1 ; ksf1: rt2,3 ; ksf2: rt4)
#pragma unroll
            for (int rr = 0; rr < 2; rr++) {
                const int rt = ksf * 2 + rr;
                if (rt > 4) continue;
                const int R0 = rt * 16 + quad * 4;
                const int quadf = (R0 >> 3) & 3;
                const int jb = R0 & 7;
#pragma unroll
                for (int ct = 0; ct < 4; ct++) {
                    const int ctg = wid * 4 + ct;
                    const int base = (ctg * 64 + quadf * 16 + m) * 8 + jb;
                    float v0 = acc[rt][ct][0], v1 = acc[rt][ct][1];
                    float v2 = acc[rt][ct][2], v3 = acc[rt][ct][3];
                    u32 H0 = bf_rne(v0), H1 = bf_rne(v1), H2 = bf_rne(v2), H3 = bf_rne(v3);
                    u32 L0 = bf_rne(v0 - __uint_as_float(H0 << 16));
                    u32 L1 = bf_rne(v1 - __uint_as_float(H1 << 16));
                    u32 L2 = bf_rne(v2 - __uint_as_float(H2 << 16));
                    u32 L3 = bf_rne(v3 - __uint_as_float(H3 << 16));
                    *(uint2*)&Ubh[base] = make_uint2(H0 | (H1 << 16), H2 | (H3 << 16));
                    *(uint2*)&Ubl[base] = make_uint2(L0 | (L1 << 16), L2 | (L3 << 16));
                }
            }
            s16x8 ubh[4], ubl[4];
#pragma unroll
            for (int ct = 0; ct < 4; ct++) {
                int uoff = ((wid * 4 + ct) * 64 + lane) * 8;
                ubh[ct] = *(const s16x8*)&Ubh[uoff];
                ubl[ct] = *(const s16x8*)&Ubl[uoff];
            }
#pragma unroll
            for (int rt = 0; rt < 5; rt++) {
#pragma unroll
                for (int ct = 0; ct < 4; ct++) {
                    acc2[rt][ct] = __builtin_amdgcn_mfma_f32_16x16x32_bf16(
                        afh[rt], ubh[ct], acc2[rt][ct], 0, 0, 0);
                    acc2[rt][ct] = __builtin_amdgcn_mfma_f32_16x16x32_bf16(
                        afh[rt], ubl[ct], acc2[rt][ct], 0, 0, 0);
                    acc2[rt][ct] = __builtin_amdgcn_mfma_f32_16x16x32_bf16(
                        afl[rt], ubh[ct], acc2[rt][ct], 0, 0, 0);
                }
            }
        }

        // ---- epilogue: wait for all waves' Ain reads, then overwrite Ain with next input ----
        __syncthreads();
#pragma unroll
        for (int rt = 0; rt < 5; rt++) {
            const int nb = rt * 16 + quad * 4;
#pragma unroll
            for (int r = 0; r < 4; r++) {
                const int n = nb + r;
                if (n >= 66) continue;
#pragma unroll
                for (int ct = 0; ct < 4; ct++) {
                    const int f = wid * 64 + ct * 16 + m;
                    const int bi = ((rt * 4 + r) * 4 + ct) * 256 + tid;
                    float v = (acc2[rt][ct][r] + bias[f]) * INVS;
                    v = tanhf(fmaf(v, gp[bi], bp[bi]));
                    if (RES) { v += carry[rt][r][ct]; carry[rt][r][ct] = v; }
                    u32 H = bf_rne(v);
                    u32 Lo = bf_rne(v - __uint_as_float(H << 16));
                    Ainh[n * 264 + f] = (u16)H;
                    Ainl[n * 264 + f] = (u16)Lo;
                    if (L == 11) Yb[n * 256 + f] = v;
                }
            }
        }
        __syncthreads();
    }
}

// ---------------- final: go = (T@gw)[:, :20] + gb + gi[:, :20]; out = go @ dct^T ----------------
__global__ __launch_bounds__(256) void final_kernel(
    const float* __restrict__ T, const float* __restrict__ gw,
    const float* __restrict__ gb, const float* __restrict__ gi,
    const float* __restrict__ dct, float* __restrict__ out) {
    __shared__ float Zt[66 * 64];
    __shared__ float gwS[256 * 20];
    __shared__ float goS[1320];
    __shared__ float dctS[400];
    const int b = blockIdx.x, tid = threadIdx.x;
    for (int idx = tid; idx < 5120; idx += 256) {
        int i = idx / 20, l = idx - i * 20;
        gwS[idx] = gw[i * 40 + l];
    }
    for (int idx = tid; idx < 400; idx += 256) dctS[idx] = dct[idx];
    for (int idx = tid; idx < 1320; idx += 256) {
        int n = idx / 20, l = idx - n * 20;
        goS[idx] = gb[l] + gi[(size_t)b * 2640 + n * 40 + l];
    }
    for (int t = 0; t < 4; t++) {
        __syncthreads();
        for (int idx = tid; idx < 66 * 64; idx += 256) {
            int mm = idx >> 6, j = idx & 63;
            Zt[idx] = T[(size_t)b * NNDIM + mm * 256 + t * 64 + j];
        }
        __syncthreads();
        for (int idx = tid; idx < 1320; idx += 256) {
            int n = idx / 20, l = idx - n * 20;
            float acc = 0.f;
#pragma unroll
            for (int j = 0; j < 64; j++)
                acc = fmaf(Zt[(n << 6) + j], gwS[(t * 64 + j) * 20 + l], acc);
            goS[idx] += acc;
        }
    }
    __syncthreads();
    for (int idx = tid; idx < 1320; idx += 256) {
        int n = idx / 20, mm = idx - n * 20;
        float o = 0.f;
#pragma unroll
        for (int l = 0; l < 20; l++)
            o = fmaf(goS[n * 20 + l], dctS[mm * 20 + l], o);   // idct = dct^T
        out[(size_t)b * 1320 + idx] = o;
    }
}

extern "C" void kernel_launch(void* const* d_in, const int* in_sizes, int n_in,
                              void* d_out, int out_size, void* d_ws, size_t ws_size,
                              hipStream_t stream) {
    const float* x        = (const float*)d_in[0];
    const float* q_w1     = (const float*)d_in[1];
    const float* q_b1     = (const float*)d_in[2];
    const float* q_w2     = (const float*)d_in[3];
    const float* q_b2     = (const float*)d_in[4];
    const float* k_w1     = (const float*)d_in[5];
    const float* k_b1     = (const float*)d_in[6];
    const float* k_w2     = (const float*)d_in[7];
    const float* k_b2     = (const float*)d_in[8];
    const float* gin_w    = (const float*)d_in[9];
    const float* gin_att  = (const float*)d_in[10];
    const float* gin_b    = (const float*)d_in[11];
    const float* bn_in_g  = (const float*)d_in[12];
    const float* bn_in_b  = (const float*)d_in[13];
    const float* blk_w    = (const float*)d_in[14];
    const float* blk_att  = (const float*)d_in[15];
    const float* blk_b    = (const float*)d_in[16];
    const float* blk_bn_g = (const float*)d_in[17];
    const float* blk_bn_b = (const float*)d_in[18];
    const float* gout_w   = (const float*)d_in[19];
    const float* gout_att = (const float*)d_in[20];
    const float* gout_b   = (const float*)d_in[21];
    float* out = (float*)d_out;

    const int B = in_sizes[0] / 3300;

    // Workspace layout
    float* dctb = (float*)d_ws;
    u16* wpk_hi = (u16*)((char*)d_ws + 4096);
    u16* wpk_lo = wpk_hi + 12 * 65536;
    u16* w2q_hi = wpk_lo + 12 * 65536;
    u16* w2q_lo = w2q_hi + 40 * 16 * 512;
    u16* w2k_hi = w2q_lo + 40 * 16 * 512;
    u16* w2k_lo = w2k_hi + 40 * 16 * 512;
    u16* atA_hi = w2k_lo + 40 * 16 * 512;
    u16* atA_lo = atA_hi + 12 * 7680;
    u16* w1q_hi = atA_lo + 12 * 7680;
    u16* w1q_lo = w1q_hi + 13 * 16 * 512;
    u16* w1k_hi = w1q_lo + 13 * 16 * 512;
    u16* w1k_lo = w1k_hi + 13 * 16 * 512;
    float* gpk  = (float*)(w1k_lo + 13 * 16 * 512);   // 12*80*256 f
    float* bpk  = gpk + 12 * 80 * 256;
    const size_t BASE = 4096 + (size_t)2 * 12 * 65536 * 2 + (size_t)4 * 40 * 16 * 512 * 2
                        + (size_t)2 * 12 * 7680 * 2 + (size_t)4 * 13 * 16 * 512 * 2
                        + (size_t)2 * 12 * 80 * 256 * 4;
    char* R = (char*)d_ws + BASE;
    size_t avail = (ws_size > BASE) ? (ws_size - BASE) : 0;

    // Per-batch floats: Y 16896 + T 16896 + gi 2640 + att 32 + q2 256 = 36720
    const size_t PER_B = 36720ull * 4ull;
    int C = B;
    while (C > 1 && (size_t)C * PER_B > avail) C >>= 1;

    dct_kernel<<<1, 512, 0, stream>>>(dctb);
    pack_w_kernel<<<(12 * 65536) / 256, 256, 0, stream>>>(blk_w, wpk_hi, wpk_lo);
    pack_w2_kernel<<<(40 * 16 * 512) / 256, 256, 0, stream>>>(q_w2, w2q_hi, w2q_lo);
    pack_w2_kernel<<<(40 * 16 * 512) / 256, 256, 0, stream>>>(k_w2, w2k_hi, w2k_lo);
    pack_att_kernel<<<(12 * 7680) / 256, 256, 0, stream>>>(blk_att, atA_hi, atA_lo);
    pack_w1_kernel<<<(13 * 16 * 512) / 256, 256, 0, stream>>>(q_w1, w1q_hi, w1q_lo);
    pack_w1_kernel<<<(13 * 16 * 512) / 256, 256, 0, stream>>>(k_w1, w1k_hi, w1k_lo);
    pack_bn_kernel<<<(12 * 80 * 256) / 256, 256, 0, stream>>>(blk_bn_g, gpk);
    pack_bn_kernel<<<(12 * 80 * 256) / 256, 256, 0, stream>>>(blk_bn_b, bpk);

    for (int c0 = 0; c0 < B; c0 += C) {
        const int Cc = (B - c0 < C) ? (B - c0) : C;
        const float* xc = x + (size_t)c0 * 3300;
        float* outc = out + (size_t)c0 * 1320;

        float* Yb  = (float*)R;                      // C*16896
        float* Tb  = Yb + (size_t)C * 16896;         // C*16896
        float* gib = Tb + (size_t)C * 16896;         // C*2640
        float* ab  = gib + (size_t)C * 2640;         // C*32
        float* q2b = ab + (size_t)C * 32;            // C*256
        // conv temporaries aliased into dead zones:
        float* k1b = Yb;                             // C*8960  (dead after conv2_mfma)
        float* k2b = Tb;                             // C*7936  (dead after att)
        float* q1b = gib;                            // C*1280  (dead before gi written)

        const int c1q = (Cc * 5 + 63) / 64, c1k = (Cc * 35 + 63) / 64;
        conv1_mfma_kernel<<<c1q + c1k, 256, 0, stream>>>(
            xc, w1q_hi, w1q_lo, w1k_hi, w1k_lo, q_b1, k_b1, q1b, k1b, Cc, c1q);
        const int c2q = (Cc + 63) / 64, c2k = (Cc * 31 + 63) / 64;
        conv2_mfma_kernel<<<c2q + c2k, 256, 0, stream>>>(
            q1b, k1b, w2q_hi, w2q_lo, w2k_hi, w2k_lo, q_b2, k_b2, q2b, k2b, Cc, c2q);
        att_kernel<<<Cc, 64, 0, stream>>>(q2b, k2b, ab);
        gcn_inp_kernel<<<Cc, 256, 0, stream>>>(xc, ab, dctb, gib);

        const int rows = Cc * FEATN;
        const int g32 = (rows + 31) / 32;

        // gin: T = gin_att @ gi (40-wide, flat); Y = tanh(bn(T @ gin_w + gin_b))
        attmul_gin_kernel<<<Cc, 256, 0, stream>>>(gib, gin_att, Tb);
        wmul_kernel<40, false><<<g32, 256, 0, stream>>>(Tb, gin_w, gin_b,
                                                        bn_in_g, bn_in_b, nullptr, Yb, rows);
        // all 12 residual layers in one resident kernel (spill-free R10 config + coalesced BN)
        trunk_kernel<<<Cc, 256, 0, stream>>>(Yb, wpk_hi, wpk_lo, atA_hi, atA_lo,
                                             blk_b, gpk, bpk);
        // gout + idct
        attmul_kernel<<<Cc, 256, 0, stream>>>(Yb, gout_att, Tb);
        final_kernel<<<Cc, 256, 0, stream>>>(Tb, gout_w, gout_b, gib, dctb, outc);
    }
}

// Round 14
// 3869.351 us; speedup vs baseline: 1.1941x; 1.1829x over previous
//
#include <hip/hip_runtime.h>
#include <math.h>

typedef unsigned short u16;
typedef unsigned int u32;

#define FEATN 66
#define HIDN 256
#define NNDIM 16896      // 66*256
#define INVS 0.9999950000374998f
#ifndef M_PI
#define M_PI 3.14159265358979323846
#endif

typedef __attribute__((ext_vector_type(4))) float f32x4;
typedef __attribute__((ext_vector_type(2))) float f32x2;
typedef __attribute__((ext_vector_type(8))) short s16x8;

__device__ __forceinline__ u32 bf_rne(float x) {
    u32 i = __float_as_uint(x);
    return (i + 0x7fffu + ((i >> 16) & 1u)) >> 16;
}

// ---------------- DCT matrix (parallel build; orthonormal: inv = transpose) ----------------
__global__ void dct_kernel(float* __restrict__ dct) {
    int t = threadIdx.x;
    if (t < 400) {
        int k = t / 20, i = t % 20;
        double w = (k == 0) ? sqrt(1.0 / 20.0) : sqrt(2.0 / 20.0);
        dct[t] = (float)(w * cos(M_PI * (i + 0.5) * k / 20.0));
    }
}

// ---------------- pack blk_w into split-bf16 MFMA B-fragment layout ----------------
// index within layer: (ks*16 + ct)*512 + lane*8 + j ; value = W[k=ks*32+(lane>>4)*8+j][n=ct*16+(lane&15)]
__global__ __launch_bounds__(256) void pack_w_kernel(
    const float* __restrict__ blk_w, u16* __restrict__ wh, u16* __restrict__ wl) {
    int gid = blockIdx.x * 256 + threadIdx.x;
    if (gid >= 12 * 65536) return;
    int layer = gid >> 16, rmd = gid & 65535;
    int ks = rmd >> 13;
    int r2 = rmd & 8191;
    int ct = r2 >> 9;
    int r3 = r2 & 511;
    int lane = r3 >> 3, j = r3 & 7;
    int k = ks * 32 + (lane >> 4) * 8 + j;
    int n = ct * 16 + (lane & 15);
    float v = blk_w[(size_t)layer * 65536 + k * 256 + n];
    u32 rhi = bf_rne(v);
    float hif = __uint_as_float(rhi << 16);
    u32 rlo = bf_rne(v - hif);
    wh[gid] = (u16)rhi;
    wl[gid] = (u16)rlo;
}

// ---------------- pack conv2 weights, K reordered t-major: k' = t*256 + h ----------------
__global__ __launch_bounds__(256) void pack_w2_kernel(
    const float* __restrict__ w2, u16* __restrict__ wh, u16* __restrict__ wl) {
    int gid = blockIdx.x * 256 + threadIdx.x;
    if (gid >= 40 * 16 * 512) return;
    int ks = gid >> 13;
    int r2 = gid & 8191;
    int ct = r2 >> 9;
    int r3 = r2 & 511;
    int lane = r3 >> 3, j = r3 & 7;
    int k = ks * 32 + (lane >> 4) * 8 + j;
    int n = ct * 16 + (lane & 15);
    int h = k & 255, t = k >> 8;
    float v = w2[(size_t)n * 1280 + h * 5 + t];
    u32 rhi = bf_rne(v);
    float hif = __uint_as_float(rhi << 16);
    u32 rlo = bf_rne(v - hif);
    wh[gid] = (u16)rhi;
    wl[gid] = (u16)rlo;
}

// ---------------- pack conv1 weights, K reordered t-major: k' = t*66 + f (pad to 416) ----------------
__global__ __launch_bounds__(256) void pack_w1_kernel(
    const float* __restrict__ w1, u16* __restrict__ wh, u16* __restrict__ wl) {
    int gid = blockIdx.x * 256 + threadIdx.x;
    if (gid >= 13 * 16 * 512) return;
    int ks = gid >> 13;
    int r2 = gid & 8191;
    int ct = r2 >> 9;
    int r3 = r2 & 511;
    int lane = r3 >> 3, j = r3 & 7;
    int k = ks * 32 + (lane >> 4) * 8 + j;
    int n = ct * 16 + (lane & 15);
    float v = 0.f;
    if (k < 396) {
        int f = k % 66, t = k / 66;
        v = w1[(size_t)n * 396 + f * 6 + t];
    }
    u32 rhi = bf_rne(v);
    float hif = __uint_as_float(rhi << 16);
    u32 rlo = bf_rne(v - hif);
    wh[gid] = (u16)rhi;
    wl[gid] = (u16)rlo;
}

// ---------------- pack blk_att into split-bf16 MFMA A-fragment layout ----------------
__global__ __launch_bounds__(256) void pack_att_kernel(
    const float* __restrict__ blk_att, u16* __restrict__ ah, u16* __restrict__ al) {
    int gid = blockIdx.x * 256 + threadIdx.x;
    if (gid >= 12 * 7680) return;
    int layer = gid / 7680, rem = gid % 7680;
    int rt = rem / 1536, rem2 = rem % 1536;
    int ks = rem2 / 512, r3 = rem2 % 512;
    int lane = r3 >> 3, j = r3 & 7;
    int n = rt * 16 + (lane & 15);
    int k = ks * 32 + (lane >> 4) * 8 + j;
    float v = (n < 66 && k < 66) ? blk_att[(size_t)layer * 4356 + n * 66 + k] : 0.f;
    u32 rhi = bf_rne(v);
    float hif = __uint_as_float(rhi << 16);
    u32 rlo = bf_rne(v - hif);
    ah[gid] = (u16)rhi;
    al[gid] = (u16)rlo;
}

// ---------------- conv1 as MFMA GEMM (split-bf16), q+k merged: N=256, K=396(pad 416) ----------------
__global__ __launch_bounds__(256, 1) void conv1_mfma_kernel(
    const float* __restrict__ x,
    const u16* __restrict__ whq, const u16* __restrict__ wlq,
    const u16* __restrict__ whk, const u16* __restrict__ wlk,
    const float* __restrict__ bq, const float* __restrict__ bk,
    float* __restrict__ q1, float* __restrict__ k1, int Cc, int nbq) {
    __shared__ u16 Ah[64 * 136];
    __shared__ u16 Al[64 * 136];
    const int tid = threadIdx.x;
    const int lane = tid & 63, wid = tid >> 6;
    const int m = lane & 15, quad = lane >> 4;
    const bool isq = ((int)blockIdx.x < nbq);
    const int bid = isq ? (int)blockIdx.x : ((int)blockIdx.x - nbq);
    const int rows = isq ? Cc * 5 : Cc * 35;
    const int row0 = bid * 64;
    const u16* wh = isq ? whq : whk;
    const u16* wl = isq ? wlq : wlk;
    const float* bias = isq ? bq : bk;
    float* out = isq ? q1 : k1;

    const int cq = tid & 31;
    const int r0t = (tid >> 5) * 8;
    int rbc[8]; bool vld[8];
#pragma unroll
    for (int s = 0; s < 8; s++) {
        int grow = row0 + r0t + s;
        int rbv;
        if (isq) { int bb = grow / 5;  rbv = bb * 3300 + 2640 + (grow - bb * 5) * 66; }
        else     { int bb = grow / 35; rbv = bb * 3300 + (grow - bb * 35) * 66; }
        vld[s] = (grow < rows);
        rbc[s] = vld[s] ? rbv : 0;
    }

    f32x4 acc[4][4];
#pragma unroll
    for (int rt = 0; rt < 4; rt++)
#pragma unroll
        for (int ct = 0; ct < 4; ct++) acc[rt][ct] = (f32x4)0.f;

    f32x2 ldA[16], ldB[16];

    auto LOADP = [&](f32x2* dst, int ph) {
        const int off = ph * 128 + cq * 4;
        const bool kok = (off < 396);
        const int o = kok ? off : 0;
#pragma unroll
        for (int s = 0; s < 8; s++) {
            const float* p = x + rbc[s] + o;
            dst[2 * s]     = *(const f32x2*)p;
            dst[2 * s + 1] = *(const f32x2*)(p + 2);
        }
    };
    auto STOREP = [&](const f32x2* src, int ph) {
        const bool kok = (ph * 128 + cq * 4) < 396;
#pragma unroll
        for (int s = 0; s < 8; s++) {
            float v0 = src[2 * s][0], v1 = src[2 * s][1];
            float v2 = src[2 * s + 1][0], v3 = src[2 * s + 1][1];
            if (!vld[s] || !kok) { v0 = v1 = v2 = v3 = 0.f; }
            u32 H0 = bf_rne(v0), H1 = bf_rne(v1), H2 = bf_rne(v2), H3 = bf_rne(v3);
            u32 L0 = bf_rne(v0 - __uint_as_float(H0 << 16));
            u32 L1 = bf_rne(v1 - __uint_as_float(H1 << 16));
            u32 L2 = bf_rne(v2 - __uint_as_float(H2 << 16));
            u32 L3 = bf_rne(v3 - __uint_as_float(H3 << 16));
            int o = (r0t + s) * 136 + cq * 4;
            *(uint2*)&Ah[o] = make_uint2(H0 | (H1 << 16), H2 | (H3 << 16));
            *(uint2*)&Al[o] = make_uint2(L0 | (L1 << 16), L2 | (L3 << 16));
        }
    };
    auto MFMAP = [&](int ph) {
#pragma unroll
        for (int ks = 0; ks < 4; ks++) {
            const int ksg = ph * 4 + ks;
            if (ksg >= 13) break;
            s16x8 ahf[4], alf[4], bhf[4], blf[4];
#pragma unroll
            for (int rt = 0; rt < 4; rt++) {
                int o2 = (rt * 16 + m) * 136 + ks * 32 + quad * 8;
                ahf[rt] = *(const s16x8*)&Ah[o2];
                alf[rt] = *(const s16x8*)&Al[o2];
            }
#pragma unroll
            for (int ct = 0; ct < 4; ct++) {
                size_t boff = ((size_t)(ksg * 16 + wid * 4 + ct)) * 512 + lane * 8;
                bhf[ct] = *(const s16x8*)&wh[boff];
                blf[ct] = *(const s16x8*)&wl[boff];
            }
#pragma unroll
            for (int rt = 0; rt < 4; rt++) {
#pragma unroll
                for (int ct = 0; ct < 4; ct++) {
                    acc[rt][ct] = __builtin_amdgcn_mfma_f32_16x16x32_bf16(
                        ahf[rt], bhf[ct], acc[rt][ct], 0, 0, 0);
                    acc[rt][ct] = __builtin_amdgcn_mfma_f32_16x16x32_bf16(
                        ahf[rt], blf[ct], acc[rt][ct], 0, 0, 0);
                    acc[rt][ct] = __builtin_amdgcn_mfma_f32_16x16x32_bf16(
                        alf[rt], bhf[ct], acc[rt][ct], 0, 0, 0);
                }
            }
        }
    };

    LOADP(ldA, 0);
    for (int ph = 0; ph < 4; ph += 2) {
        __syncthreads();
        STOREP(ldA, ph);
        LOADP(ldB, ph + 1);
        __syncthreads();
        MFMAP(ph);
        __syncthreads();
        STOREP(ldB, ph + 1);
        if (ph + 2 < 4) LOADP(ldA, ph + 2);
        __syncthreads();
        MFMAP(ph + 1);
    }

#pragma unroll
    for (int rt = 0; rt < 4; rt++) {
        int rb2 = row0 + rt * 16 + quad * 4;
#pragma unroll
        for (int r = 0; r < 4; r++) {
            int grow = rb2 + r;
            if (grow >= rows) continue;
#pragma unroll
            for (int ct = 0; ct < 4; ct++) {
                int f = wid * 64 + ct * 16 + m;
                float v = acc[rt][ct][r] + bias[f];
                out[(size_t)grow * 256 + f] = fmaxf(v, 0.f);
            }
        }
    }
}

// ---------------- conv2 as MFMA GEMM (split-bf16), q+k merged: N=256, K=1280 ----------------
__global__ __launch_bounds__(256, 1) void conv2_mfma_kernel(
    const float* __restrict__ Aq, const float* __restrict__ Ak,
    const u16* __restrict__ whq, const u16* __restrict__ wlq,
    const u16* __restrict__ whk, const u16* __restrict__ wlk,
    const float* __restrict__ bq, const float* __restrict__ bk,
    float* __restrict__ q2, float* __restrict__ k2, int Cc, int nbq) {
    __shared__ u16 Ah[64 * 136];
    __shared__ u16 Al[64 * 136];
    const int tid = threadIdx.x;
    const int lane = tid & 63, wid = tid >> 6;
    const int m = lane & 15, quad = lane >> 4;
    const bool isq = ((int)blockIdx.x < nbq);
    const int bid = isq ? (int)blockIdx.x : ((int)blockIdx.x - nbq);
    const int rows = isq ? Cc : Cc * 31;
    const int row0 = bid * 64;
    const float* Asrc = isq ? Aq : Ak;
    const u16* wh = isq ? whq : whk;
    const u16* wl = isq ? wlq : wlk;
    const float* bias = isq ? bq : bk;
    float* out = isq ? q2 : k2;

    const int cq = tid & 31;
    const int r0t = (tid >> 5) * 8;
    int rbc[8]; bool vld[8];
#pragma unroll
    for (int s = 0; s < 8; s++) {
        int grow = row0 + r0t + s;
        int rbv;
        if (isq) rbv = grow * 1280;
        else { int bb = grow / 31; rbv = bb * 8960 + (grow - bb * 31) * 256; }
        vld[s] = (grow < rows);
        rbc[s] = vld[s] ? rbv : 0;
    }

    f32x4 acc[4][4];
#pragma unroll
    for (int rt = 0; rt < 4; rt++)
#pragma unroll
        for (int ct = 0; ct < 4; ct++) acc[rt][ct] = (f32x4)0.f;

    f32x4 ldA[8], ldB[8];

    auto LOADP = [&](f32x4* dst, int ph) {
        const int off = ph * 128 + cq * 4;
#pragma unroll
        for (int s = 0; s < 8; s++)
            dst[s] = *(const f32x4*)(Asrc + rbc[s] + off);
    };
    auto STOREP = [&](const f32x4* src) {
#pragma unroll
        for (int s = 0; s < 8; s++) {
            f32x4 v = src[s];
            if (!vld[s]) v = (f32x4)0.f;
            u32 H0 = bf_rne(v[0]), H1 = bf_rne(v[1]), H2 = bf_rne(v[2]), H3 = bf_rne(v[3]);
            u32 L0 = bf_rne(v[0] - __uint_as_float(H0 << 16));
            u32 L1 = bf_rne(v[1] - __uint_as_float(H1 << 16));
            u32 L2 = bf_rne(v[2] - __uint_as_float(H2 << 16));
            u32 L3 = bf_rne(v[3] - __uint_as_float(H3 << 16));
            int o = (r0t + s) * 136 + cq * 4;
            *(uint2*)&Ah[o] = make_uint2(H0 | (H1 << 16), H2 | (H3 << 16));
            *(uint2*)&Al[o] = make_uint2(L0 | (L1 << 16), L2 | (L3 << 16));
        }
    };
    auto MFMAP = [&](int ph) {
#pragma unroll
        for (int ks = 0; ks < 4; ks++) {
            const int ksg = ph * 4 + ks;
            s16x8 ahf[4], alf[4], bhf[4], blf[4];
#pragma unroll
            for (int rt = 0; rt < 4; rt++) {
                int o2 = (rt * 16 + m) * 136 + ks * 32 + quad * 8;
                ahf[rt] = *(const s16x8*)&Ah[o2];
                alf[rt] = *(const s16x8*)&Al[o2];
            }
#pragma unroll
            for (int ct = 0; ct < 4; ct++) {
                size_t boff = ((size_t)(ksg * 16 + wid * 4 + ct)) * 512 + lane * 8;
                bhf[ct] = *(const s16x8*)&wh[boff];
                blf[ct] = *(const s16x8*)&wl[boff];
            }
#pragma unroll
            for (int rt = 0; rt < 4; rt++) {
#pragma unroll
                for (int ct = 0; ct < 4; ct++) {
                    acc[rt][ct] = __builtin_amdgcn_mfma_f32_16x16x32_bf16(
                        ahf[rt], bhf[ct], acc[rt][ct], 0, 0, 0);
                    acc[rt][ct] = __builtin_amdgcn_mfma_f32_16x16x32_bf16(
                        ahf[rt], blf[ct], acc[rt][ct], 0, 0, 0);
                    acc[rt][ct] = __builtin_amdgcn_mfma_f32_16x16x32_bf16(
                        alf[rt], bhf[ct], acc[rt][ct], 0, 0, 0);
                }
            }
        }
    };

    LOADP(ldA, 0);
    for (int ph = 0; ph < 10; ph += 2) {
        __syncthreads();
        STOREP(ldA);
        LOADP(ldB, ph + 1);
        __syncthreads();
        MFMAP(ph);
        __syncthreads();
        STOREP(ldB);
        if (ph + 2 < 10) LOADP(ldA, ph + 2);
        __syncthreads();
        MFMAP(ph + 1);
    }

#pragma unroll
    for (int rt = 0; rt < 4; rt++) {
        int rb2 = row0 + rt * 16 + quad * 4;
#pragma unroll
        for (int r = 0; r < 4; r++) {
            int grow = rb2 + r;
            if (grow >= rows) continue;
#pragma unroll
            for (int ct = 0; ct < 4; ct++) {
                int f = wid * 64 + ct * 16 + m;
                float v = acc[rt][ct][r] + bias[f];
                out[(size_t)grow * 256 + f] = fmaxf(v, 0.f);
            }
        }
    }
}

// ---------------- attention weights (one wave per batch); k2 layout [b][s][c] ----------------
__global__ void att_kernel(const float* __restrict__ q2, const float* __restrict__ k2,
                           float* __restrict__ att) {
    __shared__ float q2s[256];
    const int b = blockIdx.x, tid = threadIdx.x;
    for (int i = tid; i < 256; i += 64) q2s[i] = q2[(size_t)b * 256 + i];
    __syncthreads();
    float sc = 0.f;
    if (tid < 31) {
        const f32x4* kp = (const f32x4*)(k2 + (size_t)b * 7936 + tid * 256);
        for (int c = 0; c < 64; c++) {
            f32x4 kv = kp[c];
            sc = fmaf(q2s[c * 4 + 0], kv[0], sc);
            sc = fmaf(q2s[c * 4 + 1], kv[1], sc);
            sc = fmaf(q2s[c * 4 + 2], kv[2], sc);
            sc = fmaf(q2s[c * 4 + 3], kv[3], sc);
        }
    }
    float tot = sc;
#pragma unroll
    for (int off = 1; off < 64; off <<= 1) tot += __shfl_xor(tot, off);
    if (tid < 31) att[(size_t)b * 32 + tid] = (tot != 0.f) ? (sc / tot) : 0.f;
}

// ---------------- gcn_inp = concat(padded_query, att_final) ----------------
__global__ __launch_bounds__(256) void gcn_inp_kernel(
    const float* __restrict__ x, const float* __restrict__ att,
    const float* __restrict__ dct, float* __restrict__ ginp) {
    __shared__ float xs[3300];
    __shared__ float dctS[400];
    __shared__ float attS[31];
    const int b = blockIdx.x, tid = threadIdx.x;
    const float* xb = x + (size_t)b * 3300;
    for (int idx = tid; idx < 3300; idx += 256) xs[idx] = xb[idx];
    for (int idx = tid; idx < 400; idx += 256) dctS[idx] = dct[idx];
    if (tid < 31) attS[tid] = att[(size_t)b * 32 + tid];
    __syncthreads();
    for (int idx = tid; idx < 2640; idx += 256) {
        int n = idx / 40, l = idx - n * 40;
        float acc = 0.f;
        if (l < 20) {
#pragma unroll
            for (int l1 = 0; l1 < 20; l1++) {
                int r = (l1 < 10) ? (40 + l1) : 49;   // pidx
                acc = fmaf(xs[r * FEATN + n], dctS[l1 * 20 + l], acc);
            }
        } else {
            int j = l - 20;
            for (int s2 = 0; s2 < 31; s2++) {
                int mx = n * 31 + s2;                  // flat-reshape semantics
                int s1 = mx / 66, f1 = mx - s1 * 66;
                float inner = 0.f;
#pragma unroll
                for (int l1 = 0; l1 < 20; l1++)
                    inner = fmaf(xs[(s1 + l1) * FEATN + f1], dctS[l1 * 20 + j], inner);
                acc = fmaf(attS[s2], inner, acc);
            }
        }
        ginp[(size_t)b * 2640 + idx] = acc;
    }
}

// ---------------- attmul (gin, 40-wide): T[b] = gin_att @ gi[b] ----------------
__global__ __launch_bounds__(256) void attmul_gin_kernel(
    const float* __restrict__ ginp, const float* __restrict__ attm,
    float* __restrict__ out) {
    __shared__ float gS[2640];
    __shared__ float attS[4356];
    const int b = blockIdx.x, tid = threadIdx.x;
    for (int idx = tid; idx < 2640; idx += 256) gS[idx] = ginp[(size_t)b * 2640 + idx];
    for (int idx = tid; idx < 4356; idx += 256) attS[idx] = attm[idx];
    __syncthreads();
    for (int idx = tid; idx < 2640; idx += 256) {
        int n = idx / 40, l = idx - n * 40;
        float acc = 0.f;
        for (int mm = 0; mm < 66; mm++)
            acc = fmaf(attS[n * 66 + mm], gS[mm * 40 + l], acc);
        out[(size_t)b * 2640 + idx] = acc;
    }
}

// ---------------- attmul (256-wide): out[b] = attm @ S[b] (used once, for gout) ----------------
__global__ __launch_bounds__(256) void attmul_kernel(
    const float* __restrict__ S, const float* __restrict__ attm,
    float* __restrict__ out) {
    __shared__ float Ss[66 * 64];
    __shared__ float attS[4356];
    const int b = blockIdx.x, tid = threadIdx.x;
    for (int idx = tid; idx < 4356; idx += 256) attS[idx] = attm[idx];
    const float* Sb = S + (size_t)b * NNDIM;
    float* ob = out + (size_t)b * NNDIM;
    const int fl = tid & 63, ng = tid >> 6;
    for (int f0 = 0; f0 < 256; f0 += 64) {
        __syncthreads();
        for (int idx = tid; idx < 66 * 64; idx += 256) {
            int mm = idx >> 6, j = idx & 63;
            Ss[idx] = Sb[mm * 256 + f0 + j];
        }
        __syncthreads();
        for (int n = ng; n < 66; n += 4) {
            float acc = 0.f;
            const float* ar = &attS[n * 66];
#pragma unroll 11
            for (int mm = 0; mm < 66; mm++)
                acc = fmaf(ar[mm], Ss[(mm << 6) + fl], acc);
            ob[n * 256 + f0 + fl] = acc;
        }
    }
}

// ---------------- wmul f32 (K=40 gin layer only); W staged in LDS (40 KB) ----------------
template <int K, bool RES>
__global__ __launch_bounds__(256) void wmul_kernel(
    const float* __restrict__ Z, const float* __restrict__ W,
    const float* __restrict__ bias, const float* __restrict__ g,
    const float* __restrict__ beta, const float* __restrict__ res,
    float* __restrict__ out, int rows) {
    __shared__ float As[32 * K];
    __shared__ float Ws[K * HIDN];     // 40*256*4 = 40 KB: kills scattered global W loads
    const int tid = threadIdx.x;
    const size_t row0 = (size_t)blockIdx.x * 32;
    for (int idx = tid; idx < 32 * K; idx += 256) {
        int r = (int)row0 + idx / K;
        As[idx] = (r < rows) ? Z[row0 * K + idx] : 0.f;
    }
    for (int idx = tid; idx < K * (HIDN / 4); idx += 256)
        ((float4*)Ws)[idx] = ((const float4*)W)[idx];
    __syncthreads();
    const int fq = tid & 63, rg = tid >> 6;
    float acc[8][4];
#pragma unroll
    for (int r = 0; r < 8; r++)
#pragma unroll
        for (int c = 0; c < 4; c++) acc[r][c] = 0.f;
    for (int i = 0; i < K; i += 4) {
        float w0[4], w1[4], w2[4], w3[4];
#pragma unroll
        for (int fi = 0; fi < 4; fi++) {
            w0[fi] = Ws[(i + 0) * HIDN + fi * 64 + fq];
            w1[fi] = Ws[(i + 1) * HIDN + fi * 64 + fq];
            w2[fi] = Ws[(i + 2) * HIDN + fi * 64 + fq];
            w3[fi] = Ws[(i + 3) * HIDN + fi * 64 + fq];
        }
#pragma unroll
        for (int rr = 0; rr < 8; rr++) {
            const float4 a = *(const float4*)&As[(rg * 8 + rr) * K + i];
#pragma unroll
            for (int fi = 0; fi < 4; fi++) {
                acc[rr][fi] = fmaf(a.x, w0[fi], acc[rr][fi]);
                acc[rr][fi] = fmaf(a.y, w1[fi], acc[rr][fi]);
                acc[rr][fi] = fmaf(a.z, w2[fi], acc[rr][fi]);
                acc[rr][fi] = fmaf(a.w, w3[fi], acc[rr][fi]);
            }
        }
    }
#pragma unroll
    for (int rr = 0; rr < 8; rr++) {
        int r = (int)row0 + rg * 8 + rr;
        if (r >= rows) continue;
        int n = r % 66;
#pragma unroll
        for (int fi = 0; fi < 4; fi++) {
            int f = fi * 64 + fq;
            float v = (acc[rr][fi] + bias[f]) * INVS;
            v = tanhf(fmaf(v, g[n * 256 + f], beta[n * 256 + f]));
            if (RES) v += res[(size_t)r * 256 + f];
            out[(size_t)r * 256 + f] = v;
        }
    }
}

// ---------------- mega-fused trunk: all 12 GCN layers, 256 threads (4 waves, 4 ct/wave) ----------------
// The ONLY spill-free configuration (R6/R10: VGPR 256, FETCH = one Y pass). 512t caps VGPR
// at 128, 1024t at 64 — both spill the ~200-reg working set to scratch (R7-R9, R12:
// 2-2.5 GB/dispatch of spill traffic). Keep 256t/1-block; do not perturb.
__global__ __launch_bounds__(256, 1) void trunk_kernel(
    float* __restrict__ Y,
    const u16* __restrict__ wpk_hi, const u16* __restrict__ wpk_lo,
    const u16* __restrict__ atA_hi, const u16* __restrict__ atA_lo,
    const float* __restrict__ blk_b,
    const float* __restrict__ bn_g, const float* __restrict__ bn_b) {
    __shared__ u16 Ainh[80 * 264];      // 42240 B
    __shared__ u16 Ainl[80 * 264];
    __shared__ u16 Ubh[16 * 64 * 8];    // 16384 B (one ks-slice)
    __shared__ u16 Ubl[16 * 64 * 8];
    const int tid = threadIdx.x;
    const int lane = tid & 63, wid = tid >> 6;
    const int m = lane & 15, quad = lane >> 4;
    const int b = blockIdx.x;
    float* Yb = Y + (size_t)b * NNDIM;

    // ---- init: Y0 -> Ain (split), zero pad rows + Ub ----
    for (int idx = tid; idx < 8448; idx += 256) {      // 66 rows * 128 col-pairs
        int r = idx >> 7, c2 = (idx & 127) * 2;
        float2 yv = *(const float2*)&Yb[r * 256 + c2];
        u32 h0 = bf_rne(yv.x), h1 = bf_rne(yv.y);
        u32 l0 = bf_rne(yv.x - __uint_as_float(h0 << 16));
        u32 l1 = bf_rne(yv.y - __uint_as_float(h1 << 16));
        *(u32*)&Ainh[r * 264 + c2] = h0 | (h1 << 16);
        *(u32*)&Ainl[r * 264 + c2] = l0 | (l1 << 16);
    }
    for (int idx = tid; idx < 14 * 264; idx += 256) {
        Ainh[66 * 264 + idx] = 0; Ainl[66 * 264 + idx] = 0;
    }
    for (int idx = tid; idx < 8192; idx += 256) { Ubh[idx] = 0; Ubl[idx] = 0; }

    // carry = Y0 (f32) at this thread's epilogue positions
    float carry[5][4][4];
#pragma unroll
    for (int rt = 0; rt < 5; rt++)
#pragma unroll
        for (int r = 0; r < 4; r++) {
            int n = rt * 16 + quad * 4 + r;
#pragma unroll
            for (int ct = 0; ct < 4; ct++) {
                int f = wid * 64 + ct * 16 + m;
                carry[rt][r][ct] = (n < 66) ? Yb[n * 256 + f] : 0.f;
            }
        }
    __syncthreads();

    for (int L = 0; L < 12; L++) {
        const u16* wh  = wpk_hi + (size_t)L * 65536;
        const u16* wl  = wpk_lo + (size_t)L * 65536;
        const u16* ath = atA_hi + (size_t)L * 7680;
        const u16* atl = atA_lo + (size_t)L * 7680;
        const float* bias = blk_b + (size_t)L * 256;
        const float* g    = bn_g + (size_t)L * NNDIM;
        const float* beta = bn_b + (size_t)L * NNDIM;
        const bool RES = (L & 1);

        // ---- GEMM1: U = Ain @ W ; weight frags prefetched 1 ks ahead ----
        f32x4 acc[5][4];
#pragma unroll
        for (int rt = 0; rt < 5; rt++)
#pragma unroll
            for (int ct = 0; ct < 4; ct++) acc[rt][ct] = (f32x4)0.f;

        s16x8 pbh[4], pbl[4];
#pragma unroll
        for (int ct = 0; ct < 4; ct++) {
            size_t boff = ((size_t)(wid * 4 + ct)) * 512 + lane * 8;
            pbh[ct] = *(const s16x8*)&wh[boff];
            pbl[ct] = *(const s16x8*)&wl[boff];
        }
#pragma unroll
        for (int ks = 0; ks < 8; ks++) {
            s16x8 nbh[4], nbl[4];
            if (ks < 7) {
#pragma unroll
                for (int ct = 0; ct < 4; ct++) {
                    size_t boff = ((size_t)((ks + 1) * 16 + wid * 4 + ct)) * 512 + lane * 8;
                    nbh[ct] = *(const s16x8*)&wh[boff];
                    nbl[ct] = *(const s16x8*)&wl[boff];
                }
            }
            s16x8 ahf[5], alf[5];
#pragma unroll
            for (int rt = 0; rt < 5; rt++) {
                int o2 = (rt * 16 + m) * 264 + ks * 32 + quad * 8;
                ahf[rt] = *(const s16x8*)&Ainh[o2];
                alf[rt] = *(const s16x8*)&Ainl[o2];
            }
#pragma unroll
            for (int rt = 0; rt < 5; rt++) {
#pragma unroll
                for (int ct = 0; ct < 4; ct++) {
                    acc[rt][ct] = __builtin_amdgcn_mfma_f32_16x16x32_bf16(
                        ahf[rt], pbh[ct], acc[rt][ct], 0, 0, 0);
                    acc[rt][ct] = __builtin_amdgcn_mfma_f32_16x16x32_bf16(
                        ahf[rt], pbl[ct], acc[rt][ct], 0, 0, 0);
                    acc[rt][ct] = __builtin_amdgcn_mfma_f32_16x16x32_bf16(
                        alf[rt], pbh[ct], acc[rt][ct], 0, 0, 0);
                }
            }
            if (ks < 7) {
#pragma unroll
                for (int ct = 0; ct < 4; ct++) { pbh[ct] = nbh[ct]; pbl[ct] = nbl[ct]; }
            }
        }

        // ---- GEMM2: Z = att @ U, ks-slice at a time (scatter is intra-wave; no barrier) ----
        f32x4 acc2[5][4];
#pragma unroll
        for (int rt = 0; rt < 5; rt++)
#pragma unroll
            for (int ct = 0; ct < 4; ct++) acc2[rt][ct] = (f32x4)0.f;

#pragma unroll
        for (int ksf = 0; ksf < 3; ksf++) {
            s16x8 afh[5], afl[5];
#pragma unroll
            for (int rt = 0; rt < 5; rt++) {
                size_t aoff = ((size_t)(rt * 3 + ksf)) * 512 + lane * 8;
                afh[rt] = *(const s16x8*)&ath[aoff];
                afl[rt] = *(const s16x8*)&atl[aoff];
            }
            // scatter acc rows for this ks-slice (ksf0: rt0,1 ; ksf1: rt2,3 ; ksf2: rt4)
#pragma unroll
            for (int rr = 0; rr < 2; rr++) {
                const int rt = ksf * 2 + rr;
                if (rt > 4) continue;
                const int R0 = rt * 16 + quad * 4;
                const int quadf = (R0 >> 3) & 3;
                const int jb = R0 & 7;
#pragma unroll
                for (int ct = 0; ct < 4; ct++) {
                    const int ctg = wid * 4 + ct;
                    const int base = (ctg * 64 + quadf * 16 + m) * 8 + jb;
                    float v0 = acc[rt][ct][0], v1 = acc[rt][ct][1];
                    float v2 = acc[rt][ct][2], v3 = acc[rt][ct][3];
                    u32 H0 = bf_rne(v0), H1 = bf_rne(v1), H2 = bf_rne(v2), H3 = bf_rne(v3);
                    u32 L0 = bf_rne(v0 - __uint_as_float(H0 << 16));
                    u32 L1 = bf_rne(v1 - __uint_as_float(H1 << 16));
                    u32 L2 = bf_rne(v2 - __uint_as_float(H2 << 16));
                    u32 L3 = bf_rne(v3 - __uint_as_float(H3 << 16));
                    *(uint2*)&Ubh[base] = make_uint2(H0 | (H1 << 16), H2 | (H3 << 16));
                    *(uint2*)&Ubl[base] = make_uint2(L0 | (L1 << 16), L2 | (L3 << 16));
                }
            }
            s16x8 ubh[4], ubl[4];
#pragma unroll
            for (int ct = 0; ct < 4; ct++) {
                int uoff = ((wid * 4 + ct) * 64 + lane) * 8;
                ubh[ct] = *(const s16x8*)&Ubh[uoff];
                ubl[ct] = *(const s16x8*)&Ubl[uoff];
            }
#pragma unroll
            for (int rt = 0; rt < 5; rt++) {
#pragma unroll
                for (int ct = 0; ct < 4; ct++) {
                    acc2[rt][ct] = __builtin_amdgcn_mfma_f32_16x16x32_bf16(
                        afh[rt], ubh[ct], acc2[rt][ct], 0, 0, 0);
                    acc2[rt][ct] = __builtin_amdgcn_mfma_f32_16x16x32_bf16(
                        afh[rt], ubl[ct], acc2[rt][ct], 0, 0, 0);
                    acc2[rt][ct] = __builtin_amdgcn_mfma_f32_16x16x32_bf16(
                        afl[rt], ubh[ct], acc2[rt][ct], 0, 0, 0);
                }
            }
        }

        // ---- epilogue: wait for all waves' Ain reads, then overwrite Ain with next input ----
        __syncthreads();
#pragma unroll
        for (int rt = 0; rt < 5; rt++) {
            const int nb = rt * 16 + quad * 4;
#pragma unroll
            for (int r = 0; r < 4; r++) {
                const int n = nb + r;
                if (n >= 66) continue;
#pragma unroll
                for (int ct = 0; ct < 4; ct++) {
                    const int f = wid * 64 + ct * 16 + m;
                    float v = (acc2[rt][ct][r] + bias[f]) * INVS;
                    v = tanhf(fmaf(v, g[n * 256 + f], beta[n * 256 + f]));
                    if (RES) { v += carry[rt][r][ct]; carry[rt][r][ct] = v; }
                    u32 H = bf_rne(v);
                    u32 Lo = bf_rne(v - __uint_as_float(H << 16));
                    Ainh[n * 264 + f] = (u16)H;
                    Ainl[n * 264 + f] = (u16)Lo;
                    if (L == 11) Yb[n * 256 + f] = v;
                }
            }
        }
        __syncthreads();
    }
}

// ---------------- final: go = (T@gw)[:, :20] + gb + gi[:, :20]; out = go @ dct^T ----------------
__global__ __launch_bounds__(256) void final_kernel(
    const float* __restrict__ T, const float* __restrict__ gw,
    const float* __restrict__ gb, const float* __restrict__ gi,
    const float* __restrict__ dct, float* __restrict__ out) {
    __shared__ float Zt[66 * 64];
    __shared__ float gwS[256 * 20];
    __shared__ float goS[1320];
    __shared__ float dctS[400];
    const int b = blockIdx.x, tid = threadIdx.x;
    for (int idx = tid; idx < 5120; idx += 256) {
        int i = idx / 20, l = idx - i * 20;
        gwS[idx] = gw[i * 40 + l];
    }
    for (int idx = tid; idx < 400; idx += 256) dctS[idx] = dct[idx];
    for (int idx = tid; idx < 1320; idx += 256) {
        int n = idx / 20, l = idx - n * 20;
        goS[idx] = gb[l] + gi[(size_t)b * 2640 + n * 40 + l];
    }
    for (int t = 0; t < 4; t++) {
        __syncthreads();
        for (int idx = tid; idx < 66 * 64; idx += 256) {
            int mm = idx >> 6, j = idx & 63;
            Zt[idx] = T[(size_t)b * NNDIM + mm * 256 + t * 64 + j];
        }
        __syncthreads();
        for (int idx = tid; idx < 1320; idx += 256) {
            int n = idx / 20, l = idx - n * 20;
            float acc = 0.f;
#pragma unroll
            for (int j = 0; j < 64; j++)
                acc = fmaf(Zt[(n << 6) + j], gwS[(t * 64 + j) * 20 + l], acc);
            goS[idx] += acc;
        }
    }
    __syncthreads();
    for (int idx = tid; idx < 1320; idx += 256) {
        int n = idx / 20, mm = idx - n * 20;
        float o = 0.f;
#pragma unroll
        for (int l = 0; l < 20; l++)
            o = fmaf(goS[n * 20 + l], dctS[mm * 20 + l], o);   // idct = dct^T
        out[(size_t)b * 1320 + idx] = o;
    }
}

extern "C" void kernel_launch(void* const* d_in, const int* in_sizes, int n_in,
                              void* d_out, int out_size, void* d_ws, size_t ws_size,
                              hipStream_t stream) {
    const float* x        = (const float*)d_in[0];
    const float* q_w1     = (const float*)d_in[1];
    const float* q_b1     = (const float*)d_in[2];
    const float* q_w2     = (const float*)d_in[3];
    const float* q_b2     = (const float*)d_in[4];
    const float* k_w1     = (const float*)d_in[5];
    const float* k_b1     = (const float*)d_in[6];
    const float* k_w2     = (const float*)d_in[7];
    const float* k_b2     = (const float*)d_in[8];
    const float* gin_w    = (const float*)d_in[9];
    const float* gin_att  = (const float*)d_in[10];
    const float* gin_b    = (const float*)d_in[11];
    const float* bn_in_g  = (const float*)d_in[12];
    const float* bn_in_b  = (const float*)d_in[13];
    const float* blk_w    = (const float*)d_in[14];
    const float* blk_att  = (const float*)d_in[15];
    const float* blk_b    = (const float*)d_in[16];
    const float* blk_bn_g = (const float*)d_in[17];
    const float* blk_bn_b = (const float*)d_in[18];
    const float* gout_w   = (const float*)d_in[19];
    const float* gout_att = (const float*)d_in[20];
    const float* gout_b   = (const float*)d_in[21];
    float* out = (float*)d_out;

    const int B = in_sizes[0] / 3300;

    // Workspace layout
    float* dctb = (float*)d_ws;
    u16* wpk_hi = (u16*)((char*)d_ws + 4096);
    u16* wpk_lo = wpk_hi + 12 * 65536;
    u16* w2q_hi = wpk_lo + 12 * 65536;
    u16* w2q_lo = w2q_hi + 40 * 16 * 512;
    u16* w2k_hi = w2q_lo + 40 * 16 * 512;
    u16* w2k_lo = w2k_hi + 40 * 16 * 512;
    u16* atA_hi = w2k_lo + 40 * 16 * 512;
    u16* atA_lo = atA_hi + 12 * 7680;
    u16* w1q_hi = atA_lo + 12 * 7680;
    u16* w1q_lo = w1q_hi + 13 * 16 * 512;
    u16* w1k_hi = w1q_lo + 13 * 16 * 512;
    u16* w1k_lo = w1k_hi + 13 * 16 * 512;
    const size_t BASE = 4096 + (size_t)2 * 12 * 65536 * 2 + (size_t)4 * 40 * 16 * 512 * 2
                        + (size_t)2 * 12 * 7680 * 2 + (size_t)4 * 13 * 16 * 512 * 2;
    char* R = (char*)d_ws + BASE;
    size_t avail = (ws_size > BASE) ? (ws_size - BASE) : 0;

    // Per-batch floats: Y 16896 + T 16896 + gi 2640 + att 32 + q2 256 = 36720
    const size_t PER_B = 36720ull * 4ull;
    int C = B;
    while (C > 1 && (size_t)C * PER_B > avail) C >>= 1;

    dct_kernel<<<1, 512, 0, stream>>>(dctb);
    pack_w_kernel<<<(12 * 65536) / 256, 256, 0, stream>>>(blk_w, wpk_hi, wpk_lo);
    pack_w2_kernel<<<(40 * 16 * 512) / 256, 256, 0, stream>>>(q_w2, w2q_hi, w2q_lo);
    pack_w2_kernel<<<(40 * 16 * 512) / 256, 256, 0, stream>>>(k_w2, w2k_hi, w2k_lo);
    pack_att_kernel<<<(12 * 7680) / 256, 256, 0, stream>>>(blk_att, atA_hi, atA_lo);
    pack_w1_kernel<<<(13 * 16 * 512) / 256, 256, 0, stream>>>(q_w1, w1q_hi, w1q_lo);
    pack_w1_kernel<<<(13 * 16 * 512) / 256, 256, 0, stream>>>(k_w1, w1k_hi, w1k_lo);

    for (int c0 = 0; c0 < B; c0 += C) {
        const int Cc = (B - c0 < C) ? (B - c0) : C;
        const float* xc = x + (size_t)c0 * 3300;
        float* outc = out + (size_t)c0 * 1320;

        float* Yb  = (float*)R;                      // C*16896
        float* Tb  = Yb + (size_t)C * 16896;         // C*16896
        float* gib = Tb + (size_t)C * 16896;         // C*2640
        float* ab  = gib + (size_t)C * 2640;         // C*32
        float* q2b = ab + (size_t)C * 32;            // C*256
        // conv temporaries aliased into dead zones:
        float* k1b = Yb;                             // C*8960  (dead after conv2_mfma)
        float* k2b = Tb;                             // C*7936  (dead after att)
        float* q1b = gib;                            // C*1280  (dead before gi written)

        const int c1q = (Cc * 5 + 63) / 64, c1k = (Cc * 35 + 63) / 64;
        conv1_mfma_kernel<<<c1q + c1k, 256, 0, stream>>>(
            xc, w1q_hi, w1q_lo, w1k_hi, w1k_lo, q_b1, k_b1, q1b, k1b, Cc, c1q);
        const int c2q = (Cc + 63) / 64, c2k = (Cc * 31 + 63) / 64;
        conv2_mfma_kernel<<<c2q + c2k, 256, 0, stream>>>(
            q1b, k1b, w2q_hi, w2q_lo, w2k_hi, w2k_lo, q_b2, k_b2, q2b, k2b, Cc, c2q);
        att_kernel<<<Cc, 64, 0, stream>>>(q2b, k2b, ab);
        gcn_inp_kernel<<<Cc, 256, 0, stream>>>(xc, ab, dctb, gib);

        const int rows = Cc * FEATN;
        const int g32 = (rows + 31) / 32;

        // gin: T = gin_att @ gi (40-wide, flat); Y = tanh(bn(T @ gin_w + gin_b))
        attmul_gin_kernel<<<Cc, 256, 0, stream>>>(gib, gin_att, Tb);
        wmul_kernel<40, false><<<g32, 256, 0, stream>>>(Tb, gin_w, gin_b,
                                                        bn_in_g, bn_in_b, nullptr, Yb, rows);
        // all 12 residual layers in one resident kernel (4 waves/block — spill-free config)
        trunk_kernel<<<Cc, 256, 0, stream>>>(Yb, wpk_hi, wpk_lo, atA_hi, atA_lo,
                                             blk_b, blk_bn_g, blk_bn_b);
        // gout + idct
        attmul_kernel<<<Cc, 256, 0, stream>>>(Yb, gout_att, Tb);
        final_kernel<<<Cc, 256, 0, stream>>>(Tb, gout_w, gout_b, gib, dctb, outc);
    }
}